// Round 4
// baseline (639.331 us; speedup 1.0000x reference)
//
#include <hip/hip_runtime.h>
#include <math.h>

#define NODES 100000
#define EDGES 1250000
#define HD 64
#define NFD 16
#define CHUNK 1024
#define NCHUNK ((NODES + CHUNK - 1) / CHUNK)
#define BN_INV 0.9999950000374996f  // 1/sqrt(1+1e-5)
#define LP 65  // LDS row pitch (floats): 65 % 32 == 1 -> conflict-free scalar reads

// ---------------- graph build ----------------

__global__ void k_zero(int* __restrict__ p, int n) {
  int i = blockIdx.x * blockDim.x + threadIdx.x;
  if (i < n) p[i] = 0;
}

__global__ void k_hist(const int* __restrict__ ei, int* __restrict__ deg) {
  int e = blockIdx.x * blockDim.x + threadIdx.x;
  if (e < EDGES) atomicAdd(&deg[ei[EDGES + e]], 1);
}

__global__ void k_scan1(const int* __restrict__ deg, int* __restrict__ part) {
  __shared__ int lds[256];
  int t = threadIdx.x, b = blockIdx.x;
  int base = b * CHUNK + t * 4;
  int s = 0;
#pragma unroll
  for (int m = 0; m < 4; m++) { int i = base + m; if (i < NODES) s += deg[i]; }
  lds[t] = s; __syncthreads();
  for (int off = 128; off > 0; off >>= 1) {
    if (t < off) lds[t] += lds[t + off];
    __syncthreads();
  }
  if (t == 0) part[b] = lds[0];
}

__global__ void k_scan2(int* __restrict__ part) {
  if (threadIdx.x == 0 && blockIdx.x == 0) {
    int run = 0;
    for (int c = 0; c < NCHUNK; c++) { int v = part[c]; part[c] = run; run += v; }
  }
}

__global__ void k_scan3(const int* __restrict__ deg, const int* __restrict__ part,
                        int* __restrict__ rowptr, int* __restrict__ cur,
                        float* __restrict__ dis) {
  __shared__ int lds[256];
  int t = threadIdx.x, b = blockIdx.x;
  int base = b * CHUNK + t * 4;
  int dl[4]; int s = 0;
#pragma unroll
  for (int m = 0; m < 4; m++) { int i = base + m; dl[m] = (i < NODES) ? deg[i] : 0; s += dl[m]; }
  lds[t] = s; __syncthreads();
  for (int off = 1; off < 256; off <<= 1) {
    int add = (t >= off) ? lds[t - off] : 0;
    __syncthreads();
    lds[t] += add;
    __syncthreads();
  }
  int run = part[b] + lds[t] - s;  // exclusive prefix for this thread
#pragma unroll
  for (int m = 0; m < 4; m++) {
    int i = base + m;
    if (i < NODES) {
      rowptr[i] = run; cur[i] = run;
      dis[i] = 1.0f / sqrtf((float)(dl[m] + 1));  // GCN: indeg + self-loop
    }
    run += dl[m];
  }
  if (b == 0 && t == 0) rowptr[NODES] = EDGES;
}

// attention coeff in ORIGINAL edge order, then single 8B scattered write
__global__ void k_fillatt(const int* __restrict__ ei, const float* __restrict__ ea,
                          const float* __restrict__ cvec, const float* __restrict__ dvec,
                          const float* __restrict__ Wa, const float* __restrict__ ba,
                          int* __restrict__ cur, float2* __restrict__ sa) {
  int e = blockIdx.x * blockDim.x + threadIdx.x;
  if (e >= EDGES) return;
  int s = ei[e], d = ei[EDGES + e];
  float alin = cvec[d] + dvec[s] + ea[3 * e] * Wa[128] + ea[3 * e + 1] * Wa[129] +
               ea[3 * e + 2] * Wa[130] + ba[0];
  float lr = alin >= 0.f ? alin : 0.01f * alin;
  float a = 1.f / (1.f + expf(-lr));
  int p = atomicAdd(&cur[d], 1);
  sa[p] = make_float2(__int_as_float(s), a);
}

// ---------------- block-tiled node GEMMs: 64 nodes/block, 4 col-chunks/node ----------------

// h = x@Wn + bn -> hA ; h0 = h@Wl + bl -> hB ; cvec = h0.Wa[0:64] ; dvec = h0.Wa[64:128]
__global__ __launch_bounds__(256) void k_lin0(
    const float* __restrict__ x,
    const float* __restrict__ Wn, const float* __restrict__ bn,
    const float* __restrict__ Wl, const float* __restrict__ bl,
    const float* __restrict__ Wa,
    float* __restrict__ hA, float* __restrict__ hB,
    float* __restrict__ cvec, float* __restrict__ dvec) {
  __shared__ float sh[64 * LP];
  __shared__ float sc[4][64], sd[4][64];
  int slot = threadIdx.x & 63, cc = threadIdx.x >> 6;
  int n0 = blockIdx.x * 64 + slot;
  bool valid = n0 < NODES;
  int n = valid ? n0 : NODES - 1;
  int c0 = cc * 16;
  // stage 1: h = x@Wn + bn  (K=16)
  const float4* xr = (const float4*)(x + (size_t)n * NFD);
  float acc[16];
#pragma unroll
  for (int j = 0; j < 16; j++) acc[j] = bn[c0 + j];
#pragma unroll
  for (int kc = 0; kc < 4; kc++) {
    float4 xa = xr[kc];
    float xs[4] = {xa.x, xa.y, xa.z, xa.w};
#pragma unroll
    for (int r = 0; r < 4; r++)
#pragma unroll
      for (int j = 0; j < 16; j++)
        acc[j] = fmaf(xs[r], Wn[(kc * 4 + r) * HD + c0 + j], acc[j]);
  }
#pragma unroll
  for (int j = 0; j < 16; j++) sh[slot * LP + c0 + j] = acc[j];
  if (valid) {
    float4* ha = (float4*)(hA + (size_t)n * HD + c0);
    ha[0] = make_float4(acc[0], acc[1], acc[2], acc[3]);
    ha[1] = make_float4(acc[4], acc[5], acc[6], acc[7]);
    ha[2] = make_float4(acc[8], acc[9], acc[10], acc[11]);
    ha[3] = make_float4(acc[12], acc[13], acc[14], acc[15]);
  }
  __syncthreads();
  // stage 2: h0 = h@Wl + bl  (K=64, row from LDS)
  float a2[16];
#pragma unroll
  for (int j = 0; j < 16; j++) a2[j] = bl[c0 + j];
#pragma unroll 8
  for (int k = 0; k < 64; k++) {
    float hk = sh[slot * LP + k];
#pragma unroll
    for (int j = 0; j < 16; j++)
      a2[j] = fmaf(hk, Wl[k * HD + c0 + j], a2[j]);
  }
  float cn = 0.f, dn = 0.f;
#pragma unroll
  for (int j = 0; j < 16; j++) {
    cn = fmaf(a2[j], Wa[c0 + j], cn);
    dn = fmaf(a2[j], Wa[64 + c0 + j], dn);
  }
  if (valid) {
    float4* hb = (float4*)(hB + (size_t)n * HD + c0);
    hb[0] = make_float4(a2[0], a2[1], a2[2], a2[3]);
    hb[1] = make_float4(a2[4], a2[5], a2[6], a2[7]);
    hb[2] = make_float4(a2[8], a2[9], a2[10], a2[11]);
    hb[3] = make_float4(a2[12], a2[13], a2[14], a2[15]);
  }
  sc[cc][slot] = cn;
  sd[cc][slot] = dn;
  __syncthreads();
  if (cc == 0 && valid) {
    cvec[n] = sc[0][slot] + sc[1][slot] + sc[2][slot] + sc[3][slot];
    dvec[n] = sd[0][slot] + sd[1][slot] + sd[2][slot] + sd[3][slot];
  }
}

// fused SAGE epilogue + GCN pre-GEMM:
// t = relu(BN1(mean@Wl + hC@Wr + bl)) + hC -> hA ; hBp = dis * (t@Wg)
__global__ __launch_bounds__(256) void k_sagegcn(
    const float* __restrict__ hM, const float* __restrict__ hC,
    const float* __restrict__ Wl, const float* __restrict__ bl,
    const float* __restrict__ Wr, const float* __restrict__ Wg,
    const float* __restrict__ g, const float* __restrict__ bt,
    const float* __restrict__ dis,
    float* __restrict__ hA, float* __restrict__ hBp) {
  __shared__ float sh[64 * LP];
  int slot = threadIdx.x & 63, cc = threadIdx.x >> 6;
  int n0 = blockIdx.x * 64 + slot;
  bool valid = n0 < NODES;
  int n = valid ? n0 : NODES - 1;
  int c0 = cc * 16;
  const float4* mr = (const float4*)(hM + (size_t)n * HD);
  const float4* cr = (const float4*)(hC + (size_t)n * HD);
  float acc[16];
#pragma unroll
  for (int j = 0; j < 16; j++) acc[j] = bl[c0 + j];
#pragma unroll 4
  for (int kc = 0; kc < 16; kc++) {
    float4 am = mr[kc], ac = cr[kc];
    float ms[4] = {am.x, am.y, am.z, am.w};
    float cs[4] = {ac.x, ac.y, ac.z, ac.w};
#pragma unroll
    for (int r = 0; r < 4; r++) {
      int k = kc * 4 + r;
#pragma unroll
      for (int j = 0; j < 16; j++)
        acc[j] = fmaf(ms[r], Wl[k * HD + c0 + j], acc[j]);
#pragma unroll
      for (int j = 0; j < 16; j++)
        acc[j] = fmaf(cs[r], Wr[k * HD + c0 + j], acc[j]);
    }
  }
  // epilogue: BN + relu + residual (residual chunk re-read, L1-hot)
  float t[16];
  {
    float4 r0 = cr[cc * 4 + 0], r1 = cr[cc * 4 + 1], r2 = cr[cc * 4 + 2], r3 = cr[cc * 4 + 3];
    float rv[16] = {r0.x, r0.y, r0.z, r0.w, r1.x, r1.y, r1.z, r1.w,
                    r2.x, r2.y, r2.z, r2.w, r3.x, r3.y, r3.z, r3.w};
#pragma unroll
    for (int j = 0; j < 16; j++)
      t[j] = fmaxf(acc[j] * (g[c0 + j] * BN_INV) + bt[c0 + j], 0.f) + rv[j];
  }
#pragma unroll
  for (int j = 0; j < 16; j++) sh[slot * LP + c0 + j] = t[j];
  if (valid) {
    float4* ha = (float4*)(hA + (size_t)n * HD + c0);
    ha[0] = make_float4(t[0], t[1], t[2], t[3]);
    ha[1] = make_float4(t[4], t[5], t[6], t[7]);
    ha[2] = make_float4(t[8], t[9], t[10], t[11]);
    ha[3] = make_float4(t[12], t[13], t[14], t[15]);
  }
  __syncthreads();
  // GCN pre-GEMM from LDS t-row
  float di = dis[n];
  float a2[16];
#pragma unroll
  for (int j = 0; j < 16; j++) a2[j] = 0.f;
#pragma unroll 8
  for (int k = 0; k < 64; k++) {
    float tk = sh[slot * LP + k];
#pragma unroll
    for (int j = 0; j < 16; j++)
      a2[j] = fmaf(tk, Wg[k * HD + c0 + j], a2[j]);
  }
#pragma unroll
  for (int j = 0; j < 16; j++) a2[j] *= di;
  if (valid) {
    float4* hb = (float4*)(hBp + (size_t)n * HD + c0);
    hb[0] = make_float4(a2[0], a2[1], a2[2], a2[3]);
    hb[1] = make_float4(a2[4], a2[5], a2[6], a2[7]);
    hb[2] = make_float4(a2[8], a2[9], a2[10], a2[11]);
    hb[3] = make_float4(a2[12], a2[13], a2[14], a2[15]);
  }
}

// regressor head: out = relu(relu(hC@W1+b1)@W2+b2)@W3+b3
__global__ __launch_bounds__(256) void k_reg(
    const float* __restrict__ hC,
    const float* __restrict__ W1, const float* __restrict__ b1,
    const float* __restrict__ W2, const float* __restrict__ b2,
    const float* __restrict__ W3, const float* __restrict__ b3,
    float* __restrict__ out) {
  __shared__ float sh[64 * LP];
  __shared__ float sred[4][64];
  int slot = threadIdx.x & 63, cc = threadIdx.x >> 6;
  int n0 = blockIdx.x * 64 + slot;
  bool valid = n0 < NODES;
  int n = valid ? n0 : NODES - 1;
  int c0 = cc * 16;
  const float4* cr = (const float4*)(hC + (size_t)n * HD);
  // stage 1: t1 = relu(hC@W1 + b1)  -> LDS
  float acc[16];
#pragma unroll
  for (int j = 0; j < 16; j++) acc[j] = b1[c0 + j];
#pragma unroll 4
  for (int kc = 0; kc < 16; kc++) {
    float4 ac = cr[kc];
    float cs[4] = {ac.x, ac.y, ac.z, ac.w};
#pragma unroll
    for (int r = 0; r < 4; r++) {
      int k = kc * 4 + r;
#pragma unroll
      for (int j = 0; j < 16; j++)
        acc[j] = fmaf(cs[r], W1[k * HD + c0 + j], acc[j]);
    }
  }
#pragma unroll
  for (int j = 0; j < 16; j++) sh[slot * LP + c0 + j] = fmaxf(acc[j], 0.f);
  __syncthreads();
  // stage 2: 8 cols of t2 per thread; stage 3: partial dot with W3
  int d0 = cc * 8;
  float a2[8];
#pragma unroll
  for (int j = 0; j < 8; j++) a2[j] = b2[d0 + j];
#pragma unroll 8
  for (int k = 0; k < 64; k++) {
    float tk = sh[slot * LP + k];
#pragma unroll
    for (int j = 0; j < 8; j++)
      a2[j] = fmaf(tk, W2[k * 32 + d0 + j], a2[j]);
  }
  float part = 0.f;
#pragma unroll
  for (int j = 0; j < 8; j++) part = fmaf(fmaxf(a2[j], 0.f), W3[d0 + j], part);
  sred[cc][slot] = part;
  __syncthreads();
  if (cc == 0 && valid)
    out[n] = sred[0][slot] + sred[1][slot] + sred[2][slot] + sred[3][slot] + b3[0];
}

// ---------------- wave-per-node aggregations (float4 gathers, 4 rows/instr) ----------------

__global__ __launch_bounds__(256) void k_agg_att(
    const float2* __restrict__ sa, const int* __restrict__ rowptr,
    const float* __restrict__ hA, const float* __restrict__ hB,
    const float* __restrict__ g, const float* __restrict__ bt,
    float* __restrict__ hC) {
  int lane = threadIdx.x & 63;
  int node = __builtin_amdgcn_readfirstlane(blockIdx.x * 4 + (threadIdx.x >> 6));
  if (node >= NODES) return;
  int start = rowptr[node], end = rowptr[node + 1];
  int sub = lane >> 4;  // edge slot 0..3
  int col = lane & 15;  // float4 column group
  float4 acc0 = make_float4(0.f, 0.f, 0.f, 0.f);
  float4 acc1 = make_float4(0.f, 0.f, 0.f, 0.f);
  int last = end - 1;
  for (int m = start; m < end; m += 8) {
    int e0 = m + sub, e1 = m + sub + 4;
    float2 s0 = sa[min(e0, last)], s1 = sa[min(e1, last)];
    float w0 = (e0 < end) ? s0.y : 0.f;
    float w1 = (e1 < end) ? s1.y : 0.f;
    float4 v0 = *((const float4*)(hB + (size_t)__float_as_int(s0.x) * HD) + col);
    float4 v1 = *((const float4*)(hB + (size_t)__float_as_int(s1.x) * HD) + col);
    acc0.x = fmaf(w0, v0.x, acc0.x); acc0.y = fmaf(w0, v0.y, acc0.y);
    acc0.z = fmaf(w0, v0.z, acc0.z); acc0.w = fmaf(w0, v0.w, acc0.w);
    acc1.x = fmaf(w1, v1.x, acc1.x); acc1.y = fmaf(w1, v1.y, acc1.y);
    acc1.z = fmaf(w1, v1.z, acc1.z); acc1.w = fmaf(w1, v1.w, acc1.w);
  }
  acc0.x += acc1.x; acc0.y += acc1.y; acc0.z += acc1.z; acc0.w += acc1.w;
#pragma unroll
  for (int off = 16; off <= 32; off <<= 1) {
    acc0.x += __shfl_xor(acc0.x, off); acc0.y += __shfl_xor(acc0.y, off);
    acc0.z += __shfl_xor(acc0.z, off); acc0.w += __shfl_xor(acc0.w, off);
  }
  if (lane < 16) {
    float4 gg = ((const float4*)g)[lane];
    float4 bb = ((const float4*)bt)[lane];
    float4 ha = *((const float4*)(hA + (size_t)node * HD) + lane);
    float4 v;
    v.x = fmaxf(acc0.x * (gg.x * BN_INV) + bb.x, 0.f) + ha.x;
    v.y = fmaxf(acc0.y * (gg.y * BN_INV) + bb.y, 0.f) + ha.y;
    v.z = fmaxf(acc0.z * (gg.z * BN_INV) + bb.z, 0.f) + ha.z;
    v.w = fmaxf(acc0.w * (gg.w * BN_INV) + bb.w, 0.f) + ha.w;
    *((float4*)(hC + (size_t)node * HD) + lane) = v;
  }
}

__global__ __launch_bounds__(256) void k_agg_mean(
    const float2* __restrict__ sa, const int* __restrict__ rowptr,
    const float* __restrict__ hC, float* __restrict__ hM) {
  int lane = threadIdx.x & 63;
  int node = __builtin_amdgcn_readfirstlane(blockIdx.x * 4 + (threadIdx.x >> 6));
  if (node >= NODES) return;
  int start = rowptr[node], end = rowptr[node + 1];
  int sub = lane >> 4;
  int col = lane & 15;
  float4 acc0 = make_float4(0.f, 0.f, 0.f, 0.f);
  float4 acc1 = make_float4(0.f, 0.f, 0.f, 0.f);
  int last = end - 1;
  for (int m = start; m < end; m += 8) {
    int e0 = m + sub, e1 = m + sub + 4;
    float2 s0 = sa[min(e0, last)], s1 = sa[min(e1, last)];
    float w0 = (e0 < end) ? 1.f : 0.f;
    float w1 = (e1 < end) ? 1.f : 0.f;
    float4 v0 = *((const float4*)(hC + (size_t)__float_as_int(s0.x) * HD) + col);
    float4 v1 = *((const float4*)(hC + (size_t)__float_as_int(s1.x) * HD) + col);
    acc0.x = fmaf(w0, v0.x, acc0.x); acc0.y = fmaf(w0, v0.y, acc0.y);
    acc0.z = fmaf(w0, v0.z, acc0.z); acc0.w = fmaf(w0, v0.w, acc0.w);
    acc1.x = fmaf(w1, v1.x, acc1.x); acc1.y = fmaf(w1, v1.y, acc1.y);
    acc1.z = fmaf(w1, v1.z, acc1.z); acc1.w = fmaf(w1, v1.w, acc1.w);
  }
  acc0.x += acc1.x; acc0.y += acc1.y; acc0.z += acc1.z; acc0.w += acc1.w;
#pragma unroll
  for (int off = 16; off <= 32; off <<= 1) {
    acc0.x += __shfl_xor(acc0.x, off); acc0.y += __shfl_xor(acc0.y, off);
    acc0.z += __shfl_xor(acc0.z, off); acc0.w += __shfl_xor(acc0.w, off);
  }
  if (lane < 16) {
    float rdeg = 1.f / fmaxf((float)(end - start), 1.f);
    float4 v;
    v.x = acc0.x * rdeg; v.y = acc0.y * rdeg; v.z = acc0.z * rdeg; v.w = acc0.w * rdeg;
    *((float4*)(hM + (size_t)node * HD) + lane) = v;
  }
}

__global__ __launch_bounds__(256) void k_agg_gcn(
    const float2* __restrict__ sa, const int* __restrict__ rowptr,
    const float* __restrict__ dis,
    const float* __restrict__ hA, const float* __restrict__ hBp,
    const float* __restrict__ bg,
    const float* __restrict__ g, const float* __restrict__ bt,
    float* __restrict__ hC) {
  int lane = threadIdx.x & 63;
  int node = __builtin_amdgcn_readfirstlane(blockIdx.x * 4 + (threadIdx.x >> 6));
  if (node >= NODES) return;
  int start = rowptr[node], end = rowptr[node + 1];
  int sub = lane >> 4;
  int col = lane & 15;
  float4 acc0 = make_float4(0.f, 0.f, 0.f, 0.f);
  float4 acc1 = make_float4(0.f, 0.f, 0.f, 0.f);
  int last = end - 1;
  for (int m = start; m < end; m += 8) {
    int e0 = m + sub, e1 = m + sub + 4;
    float2 s0 = sa[min(e0, last)], s1 = sa[min(e1, last)];
    float w0 = (e0 < end) ? 1.f : 0.f;
    float w1 = (e1 < end) ? 1.f : 0.f;
    float4 v0 = *((const float4*)(hBp + (size_t)__float_as_int(s0.x) * HD) + col);
    float4 v1 = *((const float4*)(hBp + (size_t)__float_as_int(s1.x) * HD) + col);
    acc0.x = fmaf(w0, v0.x, acc0.x); acc0.y = fmaf(w0, v0.y, acc0.y);
    acc0.z = fmaf(w0, v0.z, acc0.z); acc0.w = fmaf(w0, v0.w, acc0.w);
    acc1.x = fmaf(w1, v1.x, acc1.x); acc1.y = fmaf(w1, v1.y, acc1.y);
    acc1.z = fmaf(w1, v1.z, acc1.z); acc1.w = fmaf(w1, v1.w, acc1.w);
  }
  acc0.x += acc1.x; acc0.y += acc1.y; acc0.z += acc1.z; acc0.w += acc1.w;
#pragma unroll
  for (int off = 16; off <= 32; off <<= 1) {
    acc0.x += __shfl_xor(acc0.x, off); acc0.y += __shfl_xor(acc0.y, off);
    acc0.z += __shfl_xor(acc0.z, off); acc0.w += __shfl_xor(acc0.w, off);
  }
  if (lane < 16) {
    float4 sv = *((const float4*)(hBp + (size_t)node * HD) + lane);  // self-loop
    float di = dis[node];
    float4 gg = ((const float4*)g)[lane];
    float4 bb = ((const float4*)bt)[lane];
    float4 ha = *((const float4*)(hA + (size_t)node * HD) + lane);
    float4 bgv = ((const float4*)bg)[lane];
    float4 v;
    v.x = fmaxf((di * (acc0.x + sv.x) + bgv.x) * (gg.x * BN_INV) + bb.x, 0.f) + ha.x;
    v.y = fmaxf((di * (acc0.y + sv.y) + bgv.y) * (gg.y * BN_INV) + bb.y, 0.f) + ha.y;
    v.z = fmaxf((di * (acc0.z + sv.z) + bgv.z) * (gg.z * BN_INV) + bb.z, 0.f) + ha.z;
    v.w = fmaxf((di * (acc0.w + sv.w) + bgv.w) * (gg.w * BN_INV) + bb.w, 0.f) + ha.w;
    *((float4*)(hC + (size_t)node * HD) + lane) = v;
  }
}

// ---------------- host launch ----------------

extern "C" void kernel_launch(void* const* d_in, const int* in_sizes, int n_in,
                              void* d_out, int out_size, void* d_ws, size_t ws_size,
                              hipStream_t stream) {
  const float* x      = (const float*)d_in[0];
  const float* ea     = (const float*)d_in[1];
  const int*   ei     = (const int*)d_in[2];
  const float* W_node = (const float*)d_in[3];
  const float* b_node = (const float*)d_in[4];
  // d_in[5], d_in[6]: W_edge/b_edge — unused by the reference output
  const float* W_lin0 = (const float*)d_in[7];
  const float* b_lin0 = (const float*)d_in[8];
  const float* W_att0 = (const float*)d_in[9];
  const float* b_att0 = (const float*)d_in[10];
  const float* W_sl   = (const float*)d_in[11];
  const float* b_sl   = (const float*)d_in[12];
  const float* W_sr   = (const float*)d_in[13];
  const float* W_gcn  = (const float*)d_in[14];
  const float* b_gcn  = (const float*)d_in[15];
  const float* bn_g   = (const float*)d_in[16];  // [3,64]
  const float* bn_b   = (const float*)d_in[17];
  const float* W_r1   = (const float*)d_in[18];
  const float* b_r1   = (const float*)d_in[19];
  const float* W_r2   = (const float*)d_in[20];
  const float* b_r2   = (const float*)d_in[21];
  const float* W_r3   = (const float*)d_in[22];
  const float* b_r3   = (const float*)d_in[23];
  float* out = (float*)d_out;

  char* ws = (char*)d_ws;
  size_t o = 0;
  auto alloc = [&](size_t bytes) -> void* {
    void* p = ws + o;
    o += (bytes + 255) & ~(size_t)255;
    return p;
  };
  int*    deg    = (int*)alloc(NODES * 4);
  int*    rowptr = (int*)alloc((NODES + 1) * 4);
  int*    cur    = (int*)alloc(NODES * 4);
  int*    part   = (int*)alloc(256 * 4);
  float2* sa     = (float2*)alloc((size_t)EDGES * 8);
  float*  hA     = (float*)alloc((size_t)NODES * HD * 4);
  float*  hB     = (float*)alloc((size_t)NODES * HD * 4);
  float*  hC     = (float*)alloc((size_t)NODES * HD * 4);
  float*  cvec   = (float*)alloc(NODES * 4);
  float*  dvec   = (float*)alloc(NODES * 4);
  float*  dis    = (float*)alloc(NODES * 4);
  (void)ws_size; (void)in_sizes; (void)n_in; (void)out_size;

  const int EB  = (EDGES + 255) / 256;
  const int NT  = (NODES + 63) / 64;     // tile blocks (64 nodes/block, 256 thr)
  const int NBW = (NODES + 3) / 4;       // wave-per-node (4 waves/block)

  k_zero<<<(NODES + 255) / 256, 256, 0, stream>>>(deg, NODES);
  k_hist<<<EB, 256, 0, stream>>>(ei, deg);
  k_scan1<<<NCHUNK, 256, 0, stream>>>(deg, part);
  k_scan2<<<1, 64, 0, stream>>>(part);
  k_scan3<<<NCHUNK, 256, 0, stream>>>(deg, part, rowptr, cur, dis);

  k_lin0<<<NT, 256, 0, stream>>>(x, W_node, b_node, W_lin0, b_lin0, W_att0,
                                 hA, hB, cvec, dvec);
  k_fillatt<<<EB, 256, 0, stream>>>(ei, ea, cvec, dvec, W_att0, b_att0, cur, sa);
  k_agg_att<<<NBW, 256, 0, stream>>>(sa, rowptr, hA, hB,
                                     bn_g + 0 * HD, bn_b + 0 * HD, hC);
  // hB dead -> reuse as mean buffer
  k_agg_mean<<<NBW, 256, 0, stream>>>(sa, rowptr, hC, hB);
  // fused SAGE + GCN pre-GEMM: writes t -> hA, dis*(t@Wg) -> hB
  k_sagegcn<<<NT, 256, 0, stream>>>(hB, hC, W_sl, b_sl, W_sr, W_gcn,
                                    bn_g + 1 * HD, bn_b + 1 * HD, dis, hA, hB);
  k_agg_gcn<<<NBW, 256, 0, stream>>>(sa, rowptr, dis, hA, hB, b_gcn,
                                     bn_g + 2 * HD, bn_b + 2 * HD, hC);
  k_reg<<<NT, 256, 0, stream>>>(hC, W_r1, b_r1, W_r2, b_r2, W_r3, b_r3, out);
}

// Round 5
// 530.498 us; speedup vs baseline: 1.2052x; 1.2052x over previous
//
#include <hip/hip_runtime.h>
#include <math.h>

#define NODES 100000
#define EDGES 1250000
#define HD 64
#define NFD 16
#define CHUNK 1024
#define NCHUNK ((NODES + CHUNK - 1) / CHUNK)
#define BN_INV 0.9999950000374996f  // 1/sqrt(1+1e-5)

// ---------------- graph build ----------------

__global__ void k_zero(int* __restrict__ p, int n) {
  int i = blockIdx.x * blockDim.x + threadIdx.x;
  if (i < n) p[i] = 0;
}

__global__ void k_hist(const int* __restrict__ ei, int* __restrict__ deg) {
  int e = blockIdx.x * blockDim.x + threadIdx.x;
  if (e < EDGES) atomicAdd(&deg[ei[EDGES + e]], 1);
}

__global__ void k_scan1(const int* __restrict__ deg, int* __restrict__ part) {
  __shared__ int lds[256];
  int t = threadIdx.x, b = blockIdx.x;
  int base = b * CHUNK + t * 4;
  int s = 0;
#pragma unroll
  for (int m = 0; m < 4; m++) { int i = base + m; if (i < NODES) s += deg[i]; }
  lds[t] = s; __syncthreads();
  for (int off = 128; off > 0; off >>= 1) {
    if (t < off) lds[t] += lds[t + off];
    __syncthreads();
  }
  if (t == 0) part[b] = lds[0];
}

__global__ void k_scan2(int* __restrict__ part) {
  if (threadIdx.x == 0 && blockIdx.x == 0) {
    int run = 0;
    for (int c = 0; c < NCHUNK; c++) { int v = part[c]; part[c] = run; run += v; }
  }
}

__global__ void k_scan3(const int* __restrict__ deg, const int* __restrict__ part,
                        int* __restrict__ rowptr, int* __restrict__ cur,
                        float* __restrict__ dis) {
  __shared__ int lds[256];
  int t = threadIdx.x, b = blockIdx.x;
  int base = b * CHUNK + t * 4;
  int dl[4]; int s = 0;
#pragma unroll
  for (int m = 0; m < 4; m++) { int i = base + m; dl[m] = (i < NODES) ? deg[i] : 0; s += dl[m]; }
  lds[t] = s; __syncthreads();
  for (int off = 1; off < 256; off <<= 1) {
    int add = (t >= off) ? lds[t - off] : 0;
    __syncthreads();
    lds[t] += add;
    __syncthreads();
  }
  int run = part[b] + lds[t] - s;  // exclusive prefix for this thread
#pragma unroll
  for (int m = 0; m < 4; m++) {
    int i = base + m;
    if (i < NODES) {
      rowptr[i] = run; cur[i] = run;
      dis[i] = 1.0f / sqrtf((float)(dl[m] + 1));  // GCN: indeg + self-loop
    }
    run += dl[m];
  }
  if (b == 0 && t == 0) rowptr[NODES] = EDGES;
}

// attention coeff in ORIGINAL edge order, then single 8B scattered write
__global__ void k_fillatt(const int* __restrict__ ei, const float* __restrict__ ea,
                          const float* __restrict__ cvec, const float* __restrict__ dvec,
                          const float* __restrict__ Wa, const float* __restrict__ ba,
                          int* __restrict__ cur, float2* __restrict__ sa) {
  int e = blockIdx.x * blockDim.x + threadIdx.x;
  if (e >= EDGES) return;
  int s = ei[e], d = ei[EDGES + e];
  float alin = cvec[d] + dvec[s] + ea[3 * e] * Wa[128] + ea[3 * e + 1] * Wa[129] +
               ea[3 * e + 2] * Wa[130] + ba[0];
  float lr = alin >= 0.f ? alin : 0.01f * alin;
  float a = 1.f / (1.f + expf(-lr));
  int p = atomicAdd(&cur[d], 1);
  sa[p] = make_float2(__int_as_float(s), a);
}

// ---------------- node GEMMs: thread-per-node, col-chunk via blockIdx.y ----------------
// c0 = blockIdx.y*16 is an SGPR expression -> weight loads scalarize to s_load.

// K=64 GEMM accumulate: row in float4 chunks, weights uniform
__device__ __forceinline__ void gemm_acc64(const float4* __restrict__ r,
                                           const float* __restrict__ W,
                                           int c0, float* acc) {
#pragma unroll
  for (int q = 0; q < 16; q++) {
    float4 rv = r[q];
    float sv[4] = {rv.x, rv.y, rv.z, rv.w};
#pragma unroll
    for (int t = 0; t < 4; t++)
#pragma unroll
      for (int j = 0; j < 16; j++)
        acc[j] = fmaf(sv[t], W[(q * 4 + t) * HD + c0 + j], acc[j]);
  }
}

__device__ __forceinline__ void store16(float* __restrict__ p, const float* acc) {
  float4* o = (float4*)p;
  o[0] = make_float4(acc[0], acc[1], acc[2], acc[3]);
  o[1] = make_float4(acc[4], acc[5], acc[6], acc[7]);
  o[2] = make_float4(acc[8], acc[9], acc[10], acc[11]);
  o[3] = make_float4(acc[12], acc[13], acc[14], acc[15]);
}

// h = x@Wn + bn -> hA   (K=16)
__global__ __launch_bounds__(256) void k_lin_node(
    const float* __restrict__ x, const float* __restrict__ Wn,
    const float* __restrict__ bn, float* __restrict__ hA) {
  int n = blockIdx.x * 256 + threadIdx.x;
  int c0 = blockIdx.y * 16;
  if (n >= NODES) return;
  const float4* r = (const float4*)(x + (size_t)n * NFD);
  float acc[16];
#pragma unroll
  for (int j = 0; j < 16; j++) acc[j] = bn[c0 + j];
#pragma unroll
  for (int q = 0; q < 4; q++) {
    float4 rv = r[q];
    float sv[4] = {rv.x, rv.y, rv.z, rv.w};
#pragma unroll
    for (int t = 0; t < 4; t++)
#pragma unroll
      for (int j = 0; j < 16; j++)
        acc[j] = fmaf(sv[t], Wn[(q * 4 + t) * HD + c0 + j], acc[j]);
  }
  store16(hA + (size_t)n * HD + c0, acc);
}

// h0 = hA@Wl + bl -> hB
__global__ __launch_bounds__(256) void k_lin1(
    const float* __restrict__ hA, const float* __restrict__ Wl,
    const float* __restrict__ bl, float* __restrict__ hB) {
  int n = blockIdx.x * 256 + threadIdx.x;
  int c0 = blockIdx.y * 16;
  if (n >= NODES) return;
  float acc[16];
#pragma unroll
  for (int j = 0; j < 16; j++) acc[j] = bl[c0 + j];
  gemm_acc64((const float4*)(hA + (size_t)n * HD), Wl, c0, acc);
  store16(hB + (size_t)n * HD + c0, acc);
}

// cvec/dvec: per-node dual dot of hB row with Wa[0:64] / Wa[64:128]
__global__ __launch_bounds__(256) void k_cd(
    const float* __restrict__ hB, const float* __restrict__ Wa,
    float* __restrict__ cvec, float* __restrict__ dvec) {
  int n = blockIdx.x * 256 + threadIdx.x;
  if (n >= NODES) return;
  const float4* r = (const float4*)(hB + (size_t)n * HD);
  float cn = 0.f, dn = 0.f;
#pragma unroll
  for (int q = 0; q < 16; q++) {
    float4 rv = r[q];
    float sv[4] = {rv.x, rv.y, rv.z, rv.w};
#pragma unroll
    for (int t = 0; t < 4; t++) {
      cn = fmaf(sv[t], Wa[q * 4 + t], cn);
      dn = fmaf(sv[t], Wa[64 + q * 4 + t], dn);
    }
  }
  cvec[n] = cn;
  dvec[n] = dn;
}

// t = relu(BN1(hM@Wsl + hC@Wsr + bsl)) + hC -> hA
__global__ __launch_bounds__(256) void k_sage(
    const float* __restrict__ hM, const float* __restrict__ hC,
    const float* __restrict__ Wl, const float* __restrict__ bl,
    const float* __restrict__ Wr,
    const float* __restrict__ g, const float* __restrict__ bt,
    float* __restrict__ hA) {
  int n = blockIdx.x * 256 + threadIdx.x;
  int c0 = blockIdx.y * 16;
  if (n >= NODES) return;
  float acc[16];
#pragma unroll
  for (int j = 0; j < 16; j++) acc[j] = bl[c0 + j];
  gemm_acc64((const float4*)(hM + (size_t)n * HD), Wl, c0, acc);
  gemm_acc64((const float4*)(hC + (size_t)n * HD), Wr, c0, acc);
  const float4* cr = (const float4*)(hC + (size_t)n * HD) + blockIdx.y * 4;
  float4 r0 = cr[0], r1 = cr[1], r2 = cr[2], r3 = cr[3];
  float rv[16] = {r0.x, r0.y, r0.z, r0.w, r1.x, r1.y, r1.z, r1.w,
                  r2.x, r2.y, r2.z, r2.w, r3.x, r3.y, r3.z, r3.w};
#pragma unroll
  for (int j = 0; j < 16; j++)
    acc[j] = fmaxf(acc[j] * (g[c0 + j] * BN_INV) + bt[c0 + j], 0.f) + rv[j];
  store16(hA + (size_t)n * HD + c0, acc);
}

// hBp = dis[n] * (hA @ Wg)
__global__ __launch_bounds__(256) void k_gcnmm(
    const float* __restrict__ hA, const float* __restrict__ Wg,
    const float* __restrict__ dis, float* __restrict__ hBp) {
  int n = blockIdx.x * 256 + threadIdx.x;
  int c0 = blockIdx.y * 16;
  if (n >= NODES) return;
  float acc[16];
#pragma unroll
  for (int j = 0; j < 16; j++) acc[j] = 0.f;
  gemm_acc64((const float4*)(hA + (size_t)n * HD), Wg, c0, acc);
  float di = dis[n];
#pragma unroll
  for (int j = 0; j < 16; j++) acc[j] *= di;
  store16(hBp + (size_t)n * HD + c0, acc);
}

// t1 = relu(hC@W1 + b1) -> hA
__global__ __launch_bounds__(256) void k_reg1(
    const float* __restrict__ hC, const float* __restrict__ W1,
    const float* __restrict__ b1, float* __restrict__ hA) {
  int n = blockIdx.x * 256 + threadIdx.x;
  int c0 = blockIdx.y * 16;
  if (n >= NODES) return;
  float acc[16];
#pragma unroll
  for (int j = 0; j < 16; j++) acc[j] = b1[c0 + j];
  gemm_acc64((const float4*)(hC + (size_t)n * HD), W1, c0, acc);
#pragma unroll
  for (int j = 0; j < 16; j++) acc[j] = fmaxf(acc[j], 0.f);
  store16(hA + (size_t)n * HD + c0, acc);
}

// out = relu(t1@W2+b2) . W3 + b3
__global__ __launch_bounds__(256) void k_reg2(
    const float* __restrict__ t1, const float* __restrict__ W2,
    const float* __restrict__ b2, const float* __restrict__ W3,
    const float* __restrict__ b3, float* __restrict__ out) {
  int n = blockIdx.x * 256 + threadIdx.x;
  if (n >= NODES) return;
  const float4* r = (const float4*)(t1 + (size_t)n * HD);
  float acc[32];
#pragma unroll
  for (int j = 0; j < 32; j++) acc[j] = b2[j];
#pragma unroll
  for (int q = 0; q < 16; q++) {
    float4 rv = r[q];
    float sv[4] = {rv.x, rv.y, rv.z, rv.w};
#pragma unroll
    for (int t = 0; t < 4; t++)
#pragma unroll
      for (int j = 0; j < 32; j++)
        acc[j] = fmaf(sv[t], W2[(q * 4 + t) * 32 + j], acc[j]);
  }
  float s = b3[0];
#pragma unroll
  for (int j = 0; j < 32; j++) s = fmaf(fmaxf(acc[j], 0.f), W3[j], s);
  out[n] = s;
}

// ---------------- wave-per-node aggregations (float4 gathers, 4 rows/instr) ----------------

__global__ __launch_bounds__(256) void k_agg_att(
    const float2* __restrict__ sa, const int* __restrict__ rowptr,
    const float* __restrict__ hA, const float* __restrict__ hB,
    const float* __restrict__ g, const float* __restrict__ bt,
    float* __restrict__ hC) {
  int lane = threadIdx.x & 63;
  int node = __builtin_amdgcn_readfirstlane(blockIdx.x * 4 + (threadIdx.x >> 6));
  if (node >= NODES) return;
  int start = rowptr[node], end = rowptr[node + 1];
  int sub = lane >> 4;  // edge slot 0..3
  int col = lane & 15;  // float4 column group
  float4 acc0 = make_float4(0.f, 0.f, 0.f, 0.f);
  float4 acc1 = make_float4(0.f, 0.f, 0.f, 0.f);
  int last = end - 1;
  for (int m = start; m < end; m += 8) {
    int e0 = m + sub, e1 = m + sub + 4;
    float2 s0 = sa[min(e0, last)], s1 = sa[min(e1, last)];
    float w0 = (e0 < end) ? s0.y : 0.f;
    float w1 = (e1 < end) ? s1.y : 0.f;
    float4 v0 = *((const float4*)(hB + (size_t)__float_as_int(s0.x) * HD) + col);
    float4 v1 = *((const float4*)(hB + (size_t)__float_as_int(s1.x) * HD) + col);
    acc0.x = fmaf(w0, v0.x, acc0.x); acc0.y = fmaf(w0, v0.y, acc0.y);
    acc0.z = fmaf(w0, v0.z, acc0.z); acc0.w = fmaf(w0, v0.w, acc0.w);
    acc1.x = fmaf(w1, v1.x, acc1.x); acc1.y = fmaf(w1, v1.y, acc1.y);
    acc1.z = fmaf(w1, v1.z, acc1.z); acc1.w = fmaf(w1, v1.w, acc1.w);
  }
  acc0.x += acc1.x; acc0.y += acc1.y; acc0.z += acc1.z; acc0.w += acc1.w;
#pragma unroll
  for (int off = 16; off <= 32; off <<= 1) {
    acc0.x += __shfl_xor(acc0.x, off); acc0.y += __shfl_xor(acc0.y, off);
    acc0.z += __shfl_xor(acc0.z, off); acc0.w += __shfl_xor(acc0.w, off);
  }
  if (lane < 16) {
    float4 gg = ((const float4*)g)[lane];
    float4 bb = ((const float4*)bt)[lane];
    float4 ha = *((const float4*)(hA + (size_t)node * HD) + lane);
    float4 v;
    v.x = fmaxf(acc0.x * (gg.x * BN_INV) + bb.x, 0.f) + ha.x;
    v.y = fmaxf(acc0.y * (gg.y * BN_INV) + bb.y, 0.f) + ha.y;
    v.z = fmaxf(acc0.z * (gg.z * BN_INV) + bb.z, 0.f) + ha.z;
    v.w = fmaxf(acc0.w * (gg.w * BN_INV) + bb.w, 0.f) + ha.w;
    *((float4*)(hC + (size_t)node * HD) + lane) = v;
  }
}

__global__ __launch_bounds__(256) void k_agg_mean(
    const float2* __restrict__ sa, const int* __restrict__ rowptr,
    const float* __restrict__ hC, float* __restrict__ hM) {
  int lane = threadIdx.x & 63;
  int node = __builtin_amdgcn_readfirstlane(blockIdx.x * 4 + (threadIdx.x >> 6));
  if (node >= NODES) return;
  int start = rowptr[node], end = rowptr[node + 1];
  int sub = lane >> 4;
  int col = lane & 15;
  float4 acc0 = make_float4(0.f, 0.f, 0.f, 0.f);
  float4 acc1 = make_float4(0.f, 0.f, 0.f, 0.f);
  int last = end - 1;
  for (int m = start; m < end; m += 8) {
    int e0 = m + sub, e1 = m + sub + 4;
    float2 s0 = sa[min(e0, last)], s1 = sa[min(e1, last)];
    float w0 = (e0 < end) ? 1.f : 0.f;
    float w1 = (e1 < end) ? 1.f : 0.f;
    float4 v0 = *((const float4*)(hC + (size_t)__float_as_int(s0.x) * HD) + col);
    float4 v1 = *((const float4*)(hC + (size_t)__float_as_int(s1.x) * HD) + col);
    acc0.x = fmaf(w0, v0.x, acc0.x); acc0.y = fmaf(w0, v0.y, acc0.y);
    acc0.z = fmaf(w0, v0.z, acc0.z); acc0.w = fmaf(w0, v0.w, acc0.w);
    acc1.x = fmaf(w1, v1.x, acc1.x); acc1.y = fmaf(w1, v1.y, acc1.y);
    acc1.z = fmaf(w1, v1.z, acc1.z); acc1.w = fmaf(w1, v1.w, acc1.w);
  }
  acc0.x += acc1.x; acc0.y += acc1.y; acc0.z += acc1.z; acc0.w += acc1.w;
#pragma unroll
  for (int off = 16; off <= 32; off <<= 1) {
    acc0.x += __shfl_xor(acc0.x, off); acc0.y += __shfl_xor(acc0.y, off);
    acc0.z += __shfl_xor(acc0.z, off); acc0.w += __shfl_xor(acc0.w, off);
  }
  if (lane < 16) {
    float rdeg = 1.f / fmaxf((float)(end - start), 1.f);
    float4 v;
    v.x = acc0.x * rdeg; v.y = acc0.y * rdeg; v.z = acc0.z * rdeg; v.w = acc0.w * rdeg;
    *((float4*)(hM + (size_t)node * HD) + lane) = v;
  }
}

__global__ __launch_bounds__(256) void k_agg_gcn(
    const float2* __restrict__ sa, const int* __restrict__ rowptr,
    const float* __restrict__ dis,
    const float* __restrict__ hA, const float* __restrict__ hBp,
    const float* __restrict__ bg,
    const float* __restrict__ g, const float* __restrict__ bt,
    float* __restrict__ hC) {
  int lane = threadIdx.x & 63;
  int node = __builtin_amdgcn_readfirstlane(blockIdx.x * 4 + (threadIdx.x >> 6));
  if (node >= NODES) return;
  int start = rowptr[node], end = rowptr[node + 1];
  int sub = lane >> 4;
  int col = lane & 15;
  float4 acc0 = make_float4(0.f, 0.f, 0.f, 0.f);
  float4 acc1 = make_float4(0.f, 0.f, 0.f, 0.f);
  int last = end - 1;
  for (int m = start; m < end; m += 8) {
    int e0 = m + sub, e1 = m + sub + 4;
    float2 s0 = sa[min(e0, last)], s1 = sa[min(e1, last)];
    float w0 = (e0 < end) ? 1.f : 0.f;
    float w1 = (e1 < end) ? 1.f : 0.f;
    float4 v0 = *((const float4*)(hBp + (size_t)__float_as_int(s0.x) * HD) + col);
    float4 v1 = *((const float4*)(hBp + (size_t)__float_as_int(s1.x) * HD) + col);
    acc0.x = fmaf(w0, v0.x, acc0.x); acc0.y = fmaf(w0, v0.y, acc0.y);
    acc0.z = fmaf(w0, v0.z, acc0.z); acc0.w = fmaf(w0, v0.w, acc0.w);
    acc1.x = fmaf(w1, v1.x, acc1.x); acc1.y = fmaf(w1, v1.y, acc1.y);
    acc1.z = fmaf(w1, v1.z, acc1.z); acc1.w = fmaf(w1, v1.w, acc1.w);
  }
  acc0.x += acc1.x; acc0.y += acc1.y; acc0.z += acc1.z; acc0.w += acc1.w;
#pragma unroll
  for (int off = 16; off <= 32; off <<= 1) {
    acc0.x += __shfl_xor(acc0.x, off); acc0.y += __shfl_xor(acc0.y, off);
    acc0.z += __shfl_xor(acc0.z, off); acc0.w += __shfl_xor(acc0.w, off);
  }
  if (lane < 16) {
    float4 sv = *((const float4*)(hBp + (size_t)node * HD) + lane);  // self-loop
    float di = dis[node];
    float4 gg = ((const float4*)g)[lane];
    float4 bb = ((const float4*)bt)[lane];
    float4 ha = *((const float4*)(hA + (size_t)node * HD) + lane);
    float4 bgv = ((const float4*)bg)[lane];
    float4 v;
    v.x = fmaxf((di * (acc0.x + sv.x) + bgv.x) * (gg.x * BN_INV) + bb.x, 0.f) + ha.x;
    v.y = fmaxf((di * (acc0.y + sv.y) + bgv.y) * (gg.y * BN_INV) + bb.y, 0.f) + ha.y;
    v.z = fmaxf((di * (acc0.z + sv.z) + bgv.z) * (gg.z * BN_INV) + bb.z, 0.f) + ha.z;
    v.w = fmaxf((di * (acc0.w + sv.w) + bgv.w) * (gg.w * BN_INV) + bb.w, 0.f) + ha.w;
    *((float4*)(hC + (size_t)node * HD) + lane) = v;
  }
}

// ---------------- host launch ----------------

extern "C" void kernel_launch(void* const* d_in, const int* in_sizes, int n_in,
                              void* d_out, int out_size, void* d_ws, size_t ws_size,
                              hipStream_t stream) {
  const float* x      = (const float*)d_in[0];
  const float* ea     = (const float*)d_in[1];
  const int*   ei     = (const int*)d_in[2];
  const float* W_node = (const float*)d_in[3];
  const float* b_node = (const float*)d_in[4];
  // d_in[5], d_in[6]: W_edge/b_edge — unused by the reference output
  const float* W_lin0 = (const float*)d_in[7];
  const float* b_lin0 = (const float*)d_in[8];
  const float* W_att0 = (const float*)d_in[9];
  const float* b_att0 = (const float*)d_in[10];
  const float* W_sl   = (const float*)d_in[11];
  const float* b_sl   = (const float*)d_in[12];
  const float* W_sr   = (const float*)d_in[13];
  const float* W_gcn  = (const float*)d_in[14];
  const float* b_gcn  = (const float*)d_in[15];
  const float* bn_g   = (const float*)d_in[16];  // [3,64]
  const float* bn_b   = (const float*)d_in[17];
  const float* W_r1   = (const float*)d_in[18];
  const float* b_r1   = (const float*)d_in[19];
  const float* W_r2   = (const float*)d_in[20];
  const float* b_r2   = (const float*)d_in[21];
  const float* W_r3   = (const float*)d_in[22];
  const float* b_r3   = (const float*)d_in[23];
  float* out = (float*)d_out;

  char* ws = (char*)d_ws;
  size_t o = 0;
  auto alloc = [&](size_t bytes) -> void* {
    void* p = ws + o;
    o += (bytes + 255) & ~(size_t)255;
    return p;
  };
  int*    deg    = (int*)alloc(NODES * 4);
  int*    rowptr = (int*)alloc((NODES + 1) * 4);
  int*    cur    = (int*)alloc(NODES * 4);
  int*    part   = (int*)alloc(256 * 4);
  float2* sa     = (float2*)alloc((size_t)EDGES * 8);
  float*  hA     = (float*)alloc((size_t)NODES * HD * 4);
  float*  hB     = (float*)alloc((size_t)NODES * HD * 4);
  float*  hC     = (float*)alloc((size_t)NODES * HD * 4);
  float*  cvec   = (float*)alloc(NODES * 4);
  float*  dvec   = (float*)alloc(NODES * 4);
  float*  dis    = (float*)alloc(NODES * 4);
  (void)ws_size; (void)in_sizes; (void)n_in; (void)out_size;

  const int EB  = (EDGES + 255) / 256;
  const int NB  = (NODES + 255) / 256;   // thread-per-node blocks
  const dim3 G4(NB, 4);                  // col-split GEMM grid
  const int NBW = (NODES + 3) / 4;       // wave-per-node (4 waves/block)

  k_zero<<<(NODES + 255) / 256, 256, 0, stream>>>(deg, NODES);
  k_hist<<<EB, 256, 0, stream>>>(ei, deg);
  k_scan1<<<NCHUNK, 256, 0, stream>>>(deg, part);
  k_scan2<<<1, 64, 0, stream>>>(part);
  k_scan3<<<NCHUNK, 256, 0, stream>>>(deg, part, rowptr, cur, dis);

  k_lin_node<<<G4, 256, 0, stream>>>(x, W_node, b_node, hA);
  k_lin1<<<G4, 256, 0, stream>>>(hA, W_lin0, b_lin0, hB);
  k_cd<<<NB, 256, 0, stream>>>(hB, W_att0, cvec, dvec);
  k_fillatt<<<EB, 256, 0, stream>>>(ei, ea, cvec, dvec, W_att0, b_att0, cur, sa);
  k_agg_att<<<NBW, 256, 0, stream>>>(sa, rowptr, hA, hB,
                                     bn_g + 0 * HD, bn_b + 0 * HD, hC);
  // hB (h0) dead -> reuse as mean buffer
  k_agg_mean<<<NBW, 256, 0, stream>>>(sa, rowptr, hC, hB);
  // t -> hA (h dead)
  k_sage<<<G4, 256, 0, stream>>>(hB, hC, W_sl, b_sl, W_sr,
                                 bn_g + 1 * HD, bn_b + 1 * HD, hA);
  // hBp -> hB (hM dead)
  k_gcnmm<<<G4, 256, 0, stream>>>(hA, W_gcn, dis, hB);
  k_agg_gcn<<<NBW, 256, 0, stream>>>(sa, rowptr, dis, hA, hB, b_gcn,
                                     bn_g + 2 * HD, bn_b + 2 * HD, hC);
  // t1 -> hA (t dead after agg_gcn)
  k_reg1<<<G4, 256, 0, stream>>>(hC, W_r1, b_r1, hA);
  k_reg2<<<NB, 256, 0, stream>>>(hA, W_r2, b_r2, W_r3, b_r3, out);
}

// Round 6
// 374.818 us; speedup vs baseline: 1.7057x; 1.4153x over previous
//
#include <hip/hip_runtime.h>
#include <math.h>

#define NODES 100000
#define EDGES 1250000
#define HD 64
#define NFD 16
#define CHUNK 1024
#define NCHUNK ((NODES + CHUNK - 1) / CHUNK)
#define BN_INV 0.9999950000374996f  // 1/sqrt(1+1e-5)
#define LP 65  // LDS row pitch: 65 % 32 == 1 -> 2-way bank aliasing (free)

// ---------------- graph build ----------------

__global__ void k_zero(int* __restrict__ p, int n) {
  int i = blockIdx.x * blockDim.x + threadIdx.x;
  if (i < n) p[i] = 0;
}

__global__ void k_hist(const int* __restrict__ ei, int* __restrict__ deg) {
  int e = blockIdx.x * blockDim.x + threadIdx.x;
  if (e < EDGES) atomicAdd(&deg[ei[EDGES + e]], 1);
}

__global__ void k_scan1(const int* __restrict__ deg, int* __restrict__ part) {
  __shared__ int lds[256];
  int t = threadIdx.x, b = blockIdx.x;
  int base = b * CHUNK + t * 4;
  int s = 0;
#pragma unroll
  for (int m = 0; m < 4; m++) { int i = base + m; if (i < NODES) s += deg[i]; }
  lds[t] = s; __syncthreads();
  for (int off = 128; off > 0; off >>= 1) {
    if (t < off) lds[t] += lds[t + off];
    __syncthreads();
  }
  if (t == 0) part[b] = lds[0];
}

__global__ void k_scan2(int* __restrict__ part) {
  if (threadIdx.x == 0 && blockIdx.x == 0) {
    int run = 0;
    for (int c = 0; c < NCHUNK; c++) { int v = part[c]; part[c] = run; run += v; }
  }
}

__global__ void k_scan3(const int* __restrict__ deg, const int* __restrict__ part,
                        int* __restrict__ rowptr, int* __restrict__ cur,
                        float* __restrict__ dis) {
  __shared__ int lds[256];
  int t = threadIdx.x, b = blockIdx.x;
  int base = b * CHUNK + t * 4;
  int dl[4]; int s = 0;
#pragma unroll
  for (int m = 0; m < 4; m++) { int i = base + m; dl[m] = (i < NODES) ? deg[i] : 0; s += dl[m]; }
  lds[t] = s; __syncthreads();
  for (int off = 1; off < 256; off <<= 1) {
    int add = (t >= off) ? lds[t - off] : 0;
    __syncthreads();
    lds[t] += add;
    __syncthreads();
  }
  int run = part[b] + lds[t] - s;  // exclusive prefix for this thread
#pragma unroll
  for (int m = 0; m < 4; m++) {
    int i = base + m;
    if (i < NODES) {
      rowptr[i] = run; cur[i] = run;
      dis[i] = 1.0f / sqrtf((float)(dl[m] + 1));  // GCN: indeg + self-loop
    }
    run += dl[m];
  }
  if (b == 0 && t == 0) rowptr[NODES] = EDGES;
}

// attention coeff in ORIGINAL edge order, then single 8B scattered write
__global__ void k_fillatt(const int* __restrict__ ei, const float* __restrict__ ea,
                          const float* __restrict__ cvec, const float* __restrict__ dvec,
                          const float* __restrict__ Wa, const float* __restrict__ ba,
                          int* __restrict__ cur, float2* __restrict__ sa) {
  int e = blockIdx.x * blockDim.x + threadIdx.x;
  if (e >= EDGES) return;
  int s = ei[e], d = ei[EDGES + e];
  float alin = cvec[d] + dvec[s] + ea[3 * e] * Wa[128] + ea[3 * e + 1] * Wa[129] +
               ea[3 * e + 2] * Wa[130] + ba[0];
  float lr = alin >= 0.f ? alin : 0.01f * alin;
  float a = 1.f / (1.f + expf(-lr));
  int p = atomicAdd(&cur[d], 1);
  sa[p] = make_float2(__int_as_float(s), a);
}

// ---------------- tiled node GEMMs ----------------
// 64 nodes/block x 4 col-chunk waves. cc forced to SGPR via readfirstlane ->
// all weight/bias loads scalarize to s_load (constant cache, zero VMEM issue).
// Rows bridged across stages through a 65-pitch LDS tile (2-way bank alias = free).

// stage1: h = x@Wn + bn -> hA, LDS
// stage2: h0 = h@Wl + bl -> hB ; cvec/dvec = h0 . Wa[0:64]/Wa[64:128]
__global__ __launch_bounds__(256) void k_lin0(
    const float* __restrict__ x,
    const float* __restrict__ Wn, const float* __restrict__ bn,
    const float* __restrict__ Wl, const float* __restrict__ bl,
    const float* __restrict__ Wa,
    float* __restrict__ hA, float* __restrict__ hB,
    float* __restrict__ cvec, float* __restrict__ dvec) {
  __shared__ float sh[64 * LP];
  __shared__ float sc[4][64], sd[4][64];
  int slot = threadIdx.x & 63;
  int cc = __builtin_amdgcn_readfirstlane(threadIdx.x >> 6);
  int c0 = cc * 16;
  int n0 = blockIdx.x * 64 + slot;
  bool valid = n0 < NODES;
  int n = valid ? n0 : NODES - 1;
  // stage 1 (K=16)
  const float4* xr = (const float4*)(x + (size_t)n * NFD);
  float acc[16];
#pragma unroll
  for (int j = 0; j < 16; j++) acc[j] = bn[c0 + j];
#pragma unroll
  for (int q = 0; q < 4; q++) {
    float4 xa = xr[q];
    float xs[4] = {xa.x, xa.y, xa.z, xa.w};
#pragma unroll
    for (int t = 0; t < 4; t++)
#pragma unroll
      for (int j = 0; j < 16; j++)
        acc[j] = fmaf(xs[t], Wn[(q * 4 + t) * HD + c0 + j], acc[j]);
  }
#pragma unroll
  for (int j = 0; j < 16; j++) sh[slot * LP + c0 + j] = acc[j];
  if (valid) {
    float4* o = (float4*)(hA + (size_t)n * HD + c0);
    o[0] = make_float4(acc[0], acc[1], acc[2], acc[3]);
    o[1] = make_float4(acc[4], acc[5], acc[6], acc[7]);
    o[2] = make_float4(acc[8], acc[9], acc[10], acc[11]);
    o[3] = make_float4(acc[12], acc[13], acc[14], acc[15]);
  }
  __syncthreads();
  // stage 2 (K=64 from LDS)
  float a2[16];
#pragma unroll
  for (int j = 0; j < 16; j++) a2[j] = bl[c0 + j];
#pragma unroll 8
  for (int k = 0; k < 64; k++) {
    float hk = sh[slot * LP + k];
#pragma unroll
    for (int j = 0; j < 16; j++)
      a2[j] = fmaf(hk, Wl[k * HD + c0 + j], a2[j]);
  }
  float cn = 0.f, dn = 0.f;
#pragma unroll
  for (int j = 0; j < 16; j++) {
    cn = fmaf(a2[j], Wa[c0 + j], cn);
    dn = fmaf(a2[j], Wa[64 + c0 + j], dn);
  }
  if (valid) {
    float4* o = (float4*)(hB + (size_t)n * HD + c0);
    o[0] = make_float4(a2[0], a2[1], a2[2], a2[3]);
    o[1] = make_float4(a2[4], a2[5], a2[6], a2[7]);
    o[2] = make_float4(a2[8], a2[9], a2[10], a2[11]);
    o[3] = make_float4(a2[12], a2[13], a2[14], a2[15]);
  }
  sc[cc][slot] = cn;
  sd[cc][slot] = dn;
  __syncthreads();
  if (cc == 0 && valid) {
    cvec[n] = sc[0][slot] + sc[1][slot] + sc[2][slot] + sc[3][slot];
    dvec[n] = sd[0][slot] + sd[1][slot] + sd[2][slot] + sd[3][slot];
  }
}

// t = relu(BN1(hM@Wsl + hC@Wsr + bsl)) + hC -> hA, LDS ; hBp = dis*(t@Wg) -> hD
__global__ __launch_bounds__(256) void k_sagegcn(
    const float* __restrict__ hM, const float* __restrict__ hC,
    const float* __restrict__ Wl, const float* __restrict__ bl,
    const float* __restrict__ Wr, const float* __restrict__ Wg,
    const float* __restrict__ g, const float* __restrict__ bt,
    const float* __restrict__ dis,
    float* __restrict__ hA, float* __restrict__ hD) {
  __shared__ float sh[64 * LP];
  int slot = threadIdx.x & 63;
  int cc = __builtin_amdgcn_readfirstlane(threadIdx.x >> 6);
  int c0 = cc * 16;
  int n0 = blockIdx.x * 64 + slot;
  bool valid = n0 < NODES;
  int n = valid ? n0 : NODES - 1;
  const float4* mr = (const float4*)(hM + (size_t)n * HD);
  const float4* cr = (const float4*)(hC + (size_t)n * HD);
  float acc[16];
#pragma unroll
  for (int j = 0; j < 16; j++) acc[j] = bl[c0 + j];
#pragma unroll 4
  for (int q = 0; q < 16; q++) {
    float4 am = mr[q], ac = cr[q];
    float ms[4] = {am.x, am.y, am.z, am.w};
    float cs[4] = {ac.x, ac.y, ac.z, ac.w};
#pragma unroll
    for (int t = 0; t < 4; t++) {
      int k = q * 4 + t;
#pragma unroll
      for (int j = 0; j < 16; j++)
        acc[j] = fmaf(ms[t], Wl[k * HD + c0 + j], acc[j]);
#pragma unroll
      for (int j = 0; j < 16; j++)
        acc[j] = fmaf(cs[t], Wr[k * HD + c0 + j], acc[j]);
    }
  }
  // epilogue: BN + relu + residual
  float tv[16];
  {
    float4 r0 = cr[cc * 4 + 0], r1 = cr[cc * 4 + 1], r2 = cr[cc * 4 + 2], r3 = cr[cc * 4 + 3];
    float rv[16] = {r0.x, r0.y, r0.z, r0.w, r1.x, r1.y, r1.z, r1.w,
                    r2.x, r2.y, r2.z, r2.w, r3.x, r3.y, r3.z, r3.w};
#pragma unroll
    for (int j = 0; j < 16; j++)
      tv[j] = fmaxf(acc[j] * (g[c0 + j] * BN_INV) + bt[c0 + j], 0.f) + rv[j];
  }
#pragma unroll
  for (int j = 0; j < 16; j++) sh[slot * LP + c0 + j] = tv[j];
  if (valid) {
    float4* o = (float4*)(hA + (size_t)n * HD + c0);
    o[0] = make_float4(tv[0], tv[1], tv[2], tv[3]);
    o[1] = make_float4(tv[4], tv[5], tv[6], tv[7]);
    o[2] = make_float4(tv[8], tv[9], tv[10], tv[11]);
    o[3] = make_float4(tv[12], tv[13], tv[14], tv[15]);
  }
  __syncthreads();
  // GCN pre-GEMM from LDS t-row
  float di = dis[n];
  float a2[16];
#pragma unroll
  for (int j = 0; j < 16; j++) a2[j] = 0.f;
#pragma unroll 8
  for (int k = 0; k < 64; k++) {
    float tk = sh[slot * LP + k];
#pragma unroll
    for (int j = 0; j < 16; j++)
      a2[j] = fmaf(tk, Wg[k * HD + c0 + j], a2[j]);
  }
#pragma unroll
  for (int j = 0; j < 16; j++) a2[j] *= di;
  if (valid) {
    float4* o = (float4*)(hD + (size_t)n * HD + c0);
    o[0] = make_float4(a2[0], a2[1], a2[2], a2[3]);
    o[1] = make_float4(a2[4], a2[5], a2[6], a2[7]);
    o[2] = make_float4(a2[8], a2[9], a2[10], a2[11]);
    o[3] = make_float4(a2[12], a2[13], a2[14], a2[15]);
  }
}

// regressor head fused: out = relu(relu(hC@W1+b1)@W2+b2)@W3+b3
__global__ __launch_bounds__(256) void k_reg(
    const float* __restrict__ hC,
    const float* __restrict__ W1, const float* __restrict__ b1,
    const float* __restrict__ W2, const float* __restrict__ b2,
    const float* __restrict__ W3, const float* __restrict__ b3,
    float* __restrict__ out) {
  __shared__ float sh[64 * LP];
  __shared__ float sred[4][64];
  int slot = threadIdx.x & 63;
  int cc = __builtin_amdgcn_readfirstlane(threadIdx.x >> 6);
  int c0 = cc * 16;
  int n0 = blockIdx.x * 64 + slot;
  bool valid = n0 < NODES;
  int n = valid ? n0 : NODES - 1;
  const float4* cr = (const float4*)(hC + (size_t)n * HD);
  float acc[16];
#pragma unroll
  for (int j = 0; j < 16; j++) acc[j] = b1[c0 + j];
#pragma unroll 4
  for (int q = 0; q < 16; q++) {
    float4 ac = cr[q];
    float cs[4] = {ac.x, ac.y, ac.z, ac.w};
#pragma unroll
    for (int t = 0; t < 4; t++) {
      int k = q * 4 + t;
#pragma unroll
      for (int j = 0; j < 16; j++)
        acc[j] = fmaf(cs[t], W1[k * HD + c0 + j], acc[j]);
    }
  }
#pragma unroll
  for (int j = 0; j < 16; j++) sh[slot * LP + c0 + j] = fmaxf(acc[j], 0.f);
  __syncthreads();
  // stage 2: 8 cols of t2 per cc; stage 3: partial dot with W3
  int d0 = cc * 8;
  float a2[8];
#pragma unroll
  for (int j = 0; j < 8; j++) a2[j] = b2[d0 + j];
#pragma unroll 8
  for (int k = 0; k < 64; k++) {
    float tk = sh[slot * LP + k];
#pragma unroll
    for (int j = 0; j < 8; j++)
      a2[j] = fmaf(tk, W2[k * 32 + d0 + j], a2[j]);
  }
  float part = 0.f;
#pragma unroll
  for (int j = 0; j < 8; j++) part = fmaf(fmaxf(a2[j], 0.f), W3[d0 + j], part);
  sred[cc][slot] = part;
  __syncthreads();
  if (cc == 0 && valid)
    out[n] = sred[0][slot] + sred[1][slot] + sred[2][slot] + sred[3][slot] + b3[0];
}

// ---------------- wave-per-node aggregations (float4 gathers, 4 rows/instr) ----------------

__global__ __launch_bounds__(256) void k_agg_att(
    const float2* __restrict__ sa, const int* __restrict__ rowptr,
    const float* __restrict__ hA, const float* __restrict__ hB,
    const float* __restrict__ g, const float* __restrict__ bt,
    float* __restrict__ hC) {
  int lane = threadIdx.x & 63;
  int node = __builtin_amdgcn_readfirstlane(blockIdx.x * 4 + (threadIdx.x >> 6));
  if (node >= NODES) return;
  int start = rowptr[node], end = rowptr[node + 1];
  int sub = lane >> 4;  // edge slot 0..3
  int col = lane & 15;  // float4 column group
  float4 acc0 = make_float4(0.f, 0.f, 0.f, 0.f);
  float4 acc1 = make_float4(0.f, 0.f, 0.f, 0.f);
  int last = end - 1;
  for (int m = start; m < end; m += 8) {
    int e0 = m + sub, e1 = m + sub + 4;
    float2 s0 = sa[min(e0, last)], s1 = sa[min(e1, last)];
    float w0 = (e0 < end) ? s0.y : 0.f;
    float w1 = (e1 < end) ? s1.y : 0.f;
    float4 v0 = *((const float4*)(hB + (size_t)__float_as_int(s0.x) * HD) + col);
    float4 v1 = *((const float4*)(hB + (size_t)__float_as_int(s1.x) * HD) + col);
    acc0.x = fmaf(w0, v0.x, acc0.x); acc0.y = fmaf(w0, v0.y, acc0.y);
    acc0.z = fmaf(w0, v0.z, acc0.z); acc0.w = fmaf(w0, v0.w, acc0.w);
    acc1.x = fmaf(w1, v1.x, acc1.x); acc1.y = fmaf(w1, v1.y, acc1.y);
    acc1.z = fmaf(w1, v1.z, acc1.z); acc1.w = fmaf(w1, v1.w, acc1.w);
  }
  acc0.x += acc1.x; acc0.y += acc1.y; acc0.z += acc1.z; acc0.w += acc1.w;
#pragma unroll
  for (int off = 16; off <= 32; off <<= 1) {
    acc0.x += __shfl_xor(acc0.x, off); acc0.y += __shfl_xor(acc0.y, off);
    acc0.z += __shfl_xor(acc0.z, off); acc0.w += __shfl_xor(acc0.w, off);
  }
  if (lane < 16) {
    float4 gg = ((const float4*)g)[lane];
    float4 bb = ((const float4*)bt)[lane];
    float4 ha = *((const float4*)(hA + (size_t)node * HD) + lane);
    float4 v;
    v.x = fmaxf(acc0.x * (gg.x * BN_INV) + bb.x, 0.f) + ha.x;
    v.y = fmaxf(acc0.y * (gg.y * BN_INV) + bb.y, 0.f) + ha.y;
    v.z = fmaxf(acc0.z * (gg.z * BN_INV) + bb.z, 0.f) + ha.z;
    v.w = fmaxf(acc0.w * (gg.w * BN_INV) + bb.w, 0.f) + ha.w;
    *((float4*)(hC + (size_t)node * HD) + lane) = v;
  }
}

__global__ __launch_bounds__(256) void k_agg_mean(
    const float2* __restrict__ sa, const int* __restrict__ rowptr,
    const float* __restrict__ hC, float* __restrict__ hM) {
  int lane = threadIdx.x & 63;
  int node = __builtin_amdgcn_readfirstlane(blockIdx.x * 4 + (threadIdx.x >> 6));
  if (node >= NODES) return;
  int start = rowptr[node], end = rowptr[node + 1];
  int sub = lane >> 4;
  int col = lane & 15;
  float4 acc0 = make_float4(0.f, 0.f, 0.f, 0.f);
  float4 acc1 = make_float4(0.f, 0.f, 0.f, 0.f);
  int last = end - 1;
  for (int m = start; m < end; m += 8) {
    int e0 = m + sub, e1 = m + sub + 4;
    float2 s0 = sa[min(e0, last)], s1 = sa[min(e1, last)];
    float w0 = (e0 < end) ? 1.f : 0.f;
    float w1 = (e1 < end) ? 1.f : 0.f;
    float4 v0 = *((const float4*)(hC + (size_t)__float_as_int(s0.x) * HD) + col);
    float4 v1 = *((const float4*)(hC + (size_t)__float_as_int(s1.x) * HD) + col);
    acc0.x = fmaf(w0, v0.x, acc0.x); acc0.y = fmaf(w0, v0.y, acc0.y);
    acc0.z = fmaf(w0, v0.z, acc0.z); acc0.w = fmaf(w0, v0.w, acc0.w);
    acc1.x = fmaf(w1, v1.x, acc1.x); acc1.y = fmaf(w1, v1.y, acc1.y);
    acc1.z = fmaf(w1, v1.z, acc1.z); acc1.w = fmaf(w1, v1.w, acc1.w);
  }
  acc0.x += acc1.x; acc0.y += acc1.y; acc0.z += acc1.z; acc0.w += acc1.w;
#pragma unroll
  for (int off = 16; off <= 32; off <<= 1) {
    acc0.x += __shfl_xor(acc0.x, off); acc0.y += __shfl_xor(acc0.y, off);
    acc0.z += __shfl_xor(acc0.z, off); acc0.w += __shfl_xor(acc0.w, off);
  }
  if (lane < 16) {
    float rdeg = 1.f / fmaxf((float)(end - start), 1.f);
    float4 v;
    v.x = acc0.x * rdeg; v.y = acc0.y * rdeg; v.z = acc0.z * rdeg; v.w = acc0.w * rdeg;
    *((float4*)(hM + (size_t)node * HD) + lane) = v;
  }
}

__global__ __launch_bounds__(256) void k_agg_gcn(
    const float2* __restrict__ sa, const int* __restrict__ rowptr,
    const float* __restrict__ dis,
    const float* __restrict__ hA, const float* __restrict__ hBp,
    const float* __restrict__ bg,
    const float* __restrict__ g, const float* __restrict__ bt,
    float* __restrict__ hC) {
  int lane = threadIdx.x & 63;
  int node = __builtin_amdgcn_readfirstlane(blockIdx.x * 4 + (threadIdx.x >> 6));
  if (node >= NODES) return;
  int start = rowptr[node], end = rowptr[node + 1];
  int sub = lane >> 4;
  int col = lane & 15;
  float4 acc0 = make_float4(0.f, 0.f, 0.f, 0.f);
  float4 acc1 = make_float4(0.f, 0.f, 0.f, 0.f);
  int last = end - 1;
  for (int m = start; m < end; m += 8) {
    int e0 = m + sub, e1 = m + sub + 4;
    float2 s0 = sa[min(e0, last)], s1 = sa[min(e1, last)];
    float w0 = (e0 < end) ? 1.f : 0.f;
    float w1 = (e1 < end) ? 1.f : 0.f;
    float4 v0 = *((const float4*)(hBp + (size_t)__float_as_int(s0.x) * HD) + col);
    float4 v1 = *((const float4*)(hBp + (size_t)__float_as_int(s1.x) * HD) + col);
    acc0.x = fmaf(w0, v0.x, acc0.x); acc0.y = fmaf(w0, v0.y, acc0.y);
    acc0.z = fmaf(w0, v0.z, acc0.z); acc0.w = fmaf(w0, v0.w, acc0.w);
    acc1.x = fmaf(w1, v1.x, acc1.x); acc1.y = fmaf(w1, v1.y, acc1.y);
    acc1.z = fmaf(w1, v1.z, acc1.z); acc1.w = fmaf(w1, v1.w, acc1.w);
  }
  acc0.x += acc1.x; acc0.y += acc1.y; acc0.z += acc1.z; acc0.w += acc1.w;
#pragma unroll
  for (int off = 16; off <= 32; off <<= 1) {
    acc0.x += __shfl_xor(acc0.x, off); acc0.y += __shfl_xor(acc0.y, off);
    acc0.z += __shfl_xor(acc0.z, off); acc0.w += __shfl_xor(acc0.w, off);
  }
  if (lane < 16) {
    float4 sv = *((const float4*)(hBp + (size_t)node * HD) + lane);  // self-loop
    float di = dis[node];
    float4 gg = ((const float4*)g)[lane];
    float4 bb = ((const float4*)bt)[lane];
    float4 ha = *((const float4*)(hA + (size_t)node * HD) + lane);
    float4 bgv = ((const float4*)bg)[lane];
    float4 v;
    v.x = fmaxf((di * (acc0.x + sv.x) + bgv.x) * (gg.x * BN_INV) + bb.x, 0.f) + ha.x;
    v.y = fmaxf((di * (acc0.y + sv.y) + bgv.y) * (gg.y * BN_INV) + bb.y, 0.f) + ha.y;
    v.z = fmaxf((di * (acc0.z + sv.z) + bgv.z) * (gg.z * BN_INV) + bb.z, 0.f) + ha.z;
    v.w = fmaxf((di * (acc0.w + sv.w) + bgv.w) * (gg.w * BN_INV) + bb.w, 0.f) + ha.w;
    *((float4*)(hC + (size_t)node * HD) + lane) = v;
  }
}

// ---------------- host launch ----------------

extern "C" void kernel_launch(void* const* d_in, const int* in_sizes, int n_in,
                              void* d_out, int out_size, void* d_ws, size_t ws_size,
                              hipStream_t stream) {
  const float* x      = (const float*)d_in[0];
  const float* ea     = (const float*)d_in[1];
  const int*   ei     = (const int*)d_in[2];
  const float* W_node = (const float*)d_in[3];
  const float* b_node = (const float*)d_in[4];
  // d_in[5], d_in[6]: W_edge/b_edge — unused by the reference output
  const float* W_lin0 = (const float*)d_in[7];
  const float* b_lin0 = (const float*)d_in[8];
  const float* W_att0 = (const float*)d_in[9];
  const float* b_att0 = (const float*)d_in[10];
  const float* W_sl   = (const float*)d_in[11];
  const float* b_sl   = (const float*)d_in[12];
  const float* W_sr   = (const float*)d_in[13];
  const float* W_gcn  = (const float*)d_in[14];
  const float* b_gcn  = (const float*)d_in[15];
  const float* bn_g   = (const float*)d_in[16];  // [3,64]
  const float* bn_b   = (const float*)d_in[17];
  const float* W_r1   = (const float*)d_in[18];
  const float* b_r1   = (const float*)d_in[19];
  const float* W_r2   = (const float*)d_in[20];
  const float* b_r2   = (const float*)d_in[21];
  const float* W_r3   = (const float*)d_in[22];
  const float* b_r3   = (const float*)d_in[23];
  float* out = (float*)d_out;

  char* ws = (char*)d_ws;
  size_t o = 0;
  auto alloc = [&](size_t bytes) -> void* {
    void* p = ws + o;
    o += (bytes + 255) & ~(size_t)255;
    return p;
  };
  int*    deg    = (int*)alloc(NODES * 4);
  int*    rowptr = (int*)alloc((NODES + 1) * 4);
  int*    cur    = (int*)alloc(NODES * 4);
  int*    part   = (int*)alloc(256 * 4);
  float2* sa     = (float2*)alloc((size_t)EDGES * 8);
  float*  hA     = (float*)alloc((size_t)NODES * HD * 4);
  float*  hB     = (float*)alloc((size_t)NODES * HD * 4);
  float*  hC     = (float*)alloc((size_t)NODES * HD * 4);
  float*  hD     = (float*)alloc((size_t)NODES * HD * 4);
  float*  cvec   = (float*)alloc(NODES * 4);
  float*  dvec   = (float*)alloc(NODES * 4);
  float*  dis    = (float*)alloc(NODES * 4);
  (void)ws_size; (void)in_sizes; (void)n_in; (void)out_size;

  const int EB  = (EDGES + 255) / 256;
  const int NT  = (NODES + 63) / 64;     // 64 nodes/block, 256 threads
  const int NBW = (NODES + 3) / 4;       // wave-per-node (4 waves/block)

  k_zero<<<(NODES + 255) / 256, 256, 0, stream>>>(deg, NODES);
  k_hist<<<EB, 256, 0, stream>>>(ei, deg);
  k_scan1<<<NCHUNK, 256, 0, stream>>>(deg, part);
  k_scan2<<<1, 64, 0, stream>>>(part);
  k_scan3<<<NCHUNK, 256, 0, stream>>>(deg, part, rowptr, cur, dis);

  k_lin0<<<NT, 256, 0, stream>>>(x, W_node, b_node, W_lin0, b_lin0, W_att0,
                                 hA, hB, cvec, dvec);
  k_fillatt<<<EB, 256, 0, stream>>>(ei, ea, cvec, dvec, W_att0, b_att0, cur, sa);
  k_agg_att<<<NBW, 256, 0, stream>>>(sa, rowptr, hA, hB,
                                     bn_g + 0 * HD, bn_b + 0 * HD, hC);
  // hB (h0) dead -> reuse as mean buffer
  k_agg_mean<<<NBW, 256, 0, stream>>>(sa, rowptr, hC, hB);
  // t -> hA (h dead), hBp -> hD
  k_sagegcn<<<NT, 256, 0, stream>>>(hB, hC, W_sl, b_sl, W_sr, W_gcn,
                                    bn_g + 1 * HD, bn_b + 1 * HD, dis, hA, hD);
  k_agg_gcn<<<NBW, 256, 0, stream>>>(sa, rowptr, dis, hA, hD, b_gcn,
                                     bn_g + 2 * HD, bn_b + 2 * HD, hC);
  k_reg<<<NT, 256, 0, stream>>>(hC, W_r1, b_r1, W_r2, b_r2, W_r3, b_r3, out);
}

// Round 7
// 368.856 us; speedup vs baseline: 1.7333x; 1.0162x over previous
//
#include <hip/hip_runtime.h>
#include <math.h>

#define NODES 100000
#define EDGES 1250000
#define HD 64
#define NFD 16
#define CHUNK 1024
#define NCHUNK ((NODES + CHUNK - 1) / CHUNK)
#define BN_INV 0.9999950000374996f  // 1/sqrt(1+1e-5)
#define LP 65  // LDS row pitch: 65 % 32 == 1 -> 2-way bank aliasing (free)

// ---------------- graph build ----------------

__global__ void k_hist(const int* __restrict__ ei, int* __restrict__ deg) {
  int e = blockIdx.x * blockDim.x + threadIdx.x;
  if (e < EDGES) atomicAdd(&deg[ei[EDGES + e]], 1);
}

__global__ void k_scan1(const int* __restrict__ deg, int* __restrict__ part) {
  __shared__ int lds[256];
  int t = threadIdx.x, b = blockIdx.x;
  int base = b * CHUNK + t * 4;
  int s = 0;
#pragma unroll
  for (int m = 0; m < 4; m++) { int i = base + m; if (i < NODES) s += deg[i]; }
  lds[t] = s; __syncthreads();
  for (int off = 128; off > 0; off >>= 1) {
    if (t < off) lds[t] += lds[t + off];
    __syncthreads();
  }
  if (t == 0) part[b] = lds[0];
}

__global__ void k_scan2(int* __restrict__ part) {
  if (threadIdx.x == 0 && blockIdx.x == 0) {
    int run = 0;
    for (int c = 0; c < NCHUNK; c++) { int v = part[c]; part[c] = run; run += v; }
  }
}

__global__ void k_scan3(const int* __restrict__ deg, const int* __restrict__ part,
                        int* __restrict__ rowptr, int* __restrict__ cur,
                        float* __restrict__ dis) {
  __shared__ int lds[256];
  int t = threadIdx.x, b = blockIdx.x;
  int base = b * CHUNK + t * 4;
  int dl[4]; int s = 0;
#pragma unroll
  for (int m = 0; m < 4; m++) { int i = base + m; dl[m] = (i < NODES) ? deg[i] : 0; s += dl[m]; }
  lds[t] = s; __syncthreads();
  for (int off = 1; off < 256; off <<= 1) {
    int add = (t >= off) ? lds[t - off] : 0;
    __syncthreads();
    lds[t] += add;
    __syncthreads();
  }
  int run = part[b] + lds[t] - s;  // exclusive prefix for this thread
#pragma unroll
  for (int m = 0; m < 4; m++) {
    int i = base + m;
    if (i < NODES) {
      rowptr[i] = run; cur[i] = run;
      dis[i] = 1.0f / sqrtf((float)(dl[m] + 1));  // GCN: indeg + self-loop
    }
    run += dl[m];
  }
  if (b == 0 && t == 0) rowptr[NODES] = EDGES;
}

// attention coeff in ORIGINAL edge order, then single 8B scattered write
__global__ void k_fillatt(const int* __restrict__ ei, const float* __restrict__ ea,
                          const float* __restrict__ cvec, const float* __restrict__ dvec,
                          const float* __restrict__ Wa, const float* __restrict__ ba,
                          int* __restrict__ cur, float2* __restrict__ sa) {
  int e = blockIdx.x * blockDim.x + threadIdx.x;
  if (e >= EDGES) return;
  int s = ei[e], d = ei[EDGES + e];
  float alin = cvec[d] + dvec[s] + ea[3 * e] * Wa[128] + ea[3 * e + 1] * Wa[129] +
               ea[3 * e + 2] * Wa[130] + ba[0];
  float lr = alin >= 0.f ? alin : 0.01f * alin;
  float a = 1.f / (1.f + expf(-lr));
  int p = atomicAdd(&cur[d], 1);
  sa[p] = make_float2(__int_as_float(s), a);
}

// ---------------- tiled node GEMMs ----------------
// 64 nodes/block x 4 col-chunk waves. cc forced to SGPR via readfirstlane ->
// all weight/bias loads scalarize to s_load (constant cache, zero VMEM issue).
// Rows bridged across stages through a 65-pitch LDS tile (2-way bank alias = free).

__global__ __launch_bounds__(256) void k_lin0(
    const float* __restrict__ x,
    const float* __restrict__ Wn, const float* __restrict__ bn,
    const float* __restrict__ Wl, const float* __restrict__ bl,
    const float* __restrict__ Wa,
    float* __restrict__ hA, float* __restrict__ hB,
    float* __restrict__ cvec, float* __restrict__ dvec) {
  __shared__ float sh[64 * LP];
  __shared__ float sc[4][64], sd[4][64];
  int slot = threadIdx.x & 63;
  int cc = __builtin_amdgcn_readfirstlane(threadIdx.x >> 6);
  int c0 = cc * 16;
  int n0 = blockIdx.x * 64 + slot;
  bool valid = n0 < NODES;
  int n = valid ? n0 : NODES - 1;
  // stage 1 (K=16)
  const float4* xr = (const float4*)(x + (size_t)n * NFD);
  float acc[16];
#pragma unroll
  for (int j = 0; j < 16; j++) acc[j] = bn[c0 + j];
#pragma unroll
  for (int q = 0; q < 4; q++) {
    float4 xa = xr[q];
    float xs[4] = {xa.x, xa.y, xa.z, xa.w};
#pragma unroll
    for (int t = 0; t < 4; t++)
#pragma unroll
      for (int j = 0; j < 16; j++)
        acc[j] = fmaf(xs[t], Wn[(q * 4 + t) * HD + c0 + j], acc[j]);
  }
#pragma unroll
  for (int j = 0; j < 16; j++) sh[slot * LP + c0 + j] = acc[j];
  if (valid) {
    float4* o = (float4*)(hA + (size_t)n * HD + c0);
    o[0] = make_float4(acc[0], acc[1], acc[2], acc[3]);
    o[1] = make_float4(acc[4], acc[5], acc[6], acc[7]);
    o[2] = make_float4(acc[8], acc[9], acc[10], acc[11]);
    o[3] = make_float4(acc[12], acc[13], acc[14], acc[15]);
  }
  __syncthreads();
  // stage 2 (K=64 from LDS)
  float a2[16];
#pragma unroll
  for (int j = 0; j < 16; j++) a2[j] = bl[c0 + j];
#pragma unroll 8
  for (int k = 0; k < 64; k++) {
    float hk = sh[slot * LP + k];
#pragma unroll
    for (int j = 0; j < 16; j++)
      a2[j] = fmaf(hk, Wl[k * HD + c0 + j], a2[j]);
  }
  float cn = 0.f, dn = 0.f;
#pragma unroll
  for (int j = 0; j < 16; j++) {
    cn = fmaf(a2[j], Wa[c0 + j], cn);
    dn = fmaf(a2[j], Wa[64 + c0 + j], dn);
  }
  if (valid) {
    float4* o = (float4*)(hB + (size_t)n * HD + c0);
    o[0] = make_float4(a2[0], a2[1], a2[2], a2[3]);
    o[1] = make_float4(a2[4], a2[5], a2[6], a2[7]);
    o[2] = make_float4(a2[8], a2[9], a2[10], a2[11]);
    o[3] = make_float4(a2[12], a2[13], a2[14], a2[15]);
  }
  sc[cc][slot] = cn;
  sd[cc][slot] = dn;
  __syncthreads();
  if (cc == 0 && valid) {
    cvec[n] = sc[0][slot] + sc[1][slot] + sc[2][slot] + sc[3][slot];
    dvec[n] = sd[0][slot] + sd[1][slot] + sd[2][slot] + sd[3][slot];
  }
}

// t = relu(BN1(hM@Wsl + hC@Wsr + bsl)) + hC -> hA, LDS ; hBp = dis*(t@Wg) -> hD
__global__ __launch_bounds__(256) void k_sagegcn(
    const float* __restrict__ hM, const float* __restrict__ hC,
    const float* __restrict__ Wl, const float* __restrict__ bl,
    const float* __restrict__ Wr, const float* __restrict__ Wg,
    const float* __restrict__ g, const float* __restrict__ bt,
    const float* __restrict__ dis,
    float* __restrict__ hA, float* __restrict__ hD) {
  __shared__ float sh[64 * LP];
  int slot = threadIdx.x & 63;
  int cc = __builtin_amdgcn_readfirstlane(threadIdx.x >> 6);
  int c0 = cc * 16;
  int n0 = blockIdx.x * 64 + slot;
  bool valid = n0 < NODES;
  int n = valid ? n0 : NODES - 1;
  const float4* mr = (const float4*)(hM + (size_t)n * HD);
  const float4* cr = (const float4*)(hC + (size_t)n * HD);
  float acc[16];
#pragma unroll
  for (int j = 0; j < 16; j++) acc[j] = bl[c0 + j];
#pragma unroll 4
  for (int q = 0; q < 16; q++) {
    float4 am = mr[q], ac = cr[q];
    float ms[4] = {am.x, am.y, am.z, am.w};
    float cs[4] = {ac.x, ac.y, ac.z, ac.w};
#pragma unroll
    for (int t = 0; t < 4; t++) {
      int k = q * 4 + t;
#pragma unroll
      for (int j = 0; j < 16; j++)
        acc[j] = fmaf(ms[t], Wl[k * HD + c0 + j], acc[j]);
#pragma unroll
      for (int j = 0; j < 16; j++)
        acc[j] = fmaf(cs[t], Wr[k * HD + c0 + j], acc[j]);
    }
  }
  // epilogue: BN + relu + residual
  float tv[16];
  {
    float4 r0 = cr[cc * 4 + 0], r1 = cr[cc * 4 + 1], r2 = cr[cc * 4 + 2], r3 = cr[cc * 4 + 3];
    float rv[16] = {r0.x, r0.y, r0.z, r0.w, r1.x, r1.y, r1.z, r1.w,
                    r2.x, r2.y, r2.z, r2.w, r3.x, r3.y, r3.z, r3.w};
#pragma unroll
    for (int j = 0; j < 16; j++)
      tv[j] = fmaxf(acc[j] * (g[c0 + j] * BN_INV) + bt[c0 + j], 0.f) + rv[j];
  }
#pragma unroll
  for (int j = 0; j < 16; j++) sh[slot * LP + c0 + j] = tv[j];
  if (valid) {
    float4* o = (float4*)(hA + (size_t)n * HD + c0);
    o[0] = make_float4(tv[0], tv[1], tv[2], tv[3]);
    o[1] = make_float4(tv[4], tv[5], tv[6], tv[7]);
    o[2] = make_float4(tv[8], tv[9], tv[10], tv[11]);
    o[3] = make_float4(tv[12], tv[13], tv[14], tv[15]);
  }
  __syncthreads();
  // GCN pre-GEMM from LDS t-row
  float di = dis[n];
  float a2[16];
#pragma unroll
  for (int j = 0; j < 16; j++) a2[j] = 0.f;
#pragma unroll 8
  for (int k = 0; k < 64; k++) {
    float tk = sh[slot * LP + k];
#pragma unroll
    for (int j = 0; j < 16; j++)
      a2[j] = fmaf(tk, Wg[k * HD + c0 + j], a2[j]);
  }
#pragma unroll
  for (int j = 0; j < 16; j++) a2[j] *= di;
  if (valid) {
    float4* o = (float4*)(hD + (size_t)n * HD + c0);
    o[0] = make_float4(a2[0], a2[1], a2[2], a2[3]);
    o[1] = make_float4(a2[4], a2[5], a2[6], a2[7]);
    o[2] = make_float4(a2[8], a2[9], a2[10], a2[11]);
    o[3] = make_float4(a2[12], a2[13], a2[14], a2[15]);
  }
}

// regressor head fused: out = relu(relu(hC@W1+b1)@W2+b2)@W3+b3
__global__ __launch_bounds__(256) void k_reg(
    const float* __restrict__ hC,
    const float* __restrict__ W1, const float* __restrict__ b1,
    const float* __restrict__ W2, const float* __restrict__ b2,
    const float* __restrict__ W3, const float* __restrict__ b3,
    float* __restrict__ out) {
  __shared__ float sh[64 * LP];
  __shared__ float sred[4][64];
  int slot = threadIdx.x & 63;
  int cc = __builtin_amdgcn_readfirstlane(threadIdx.x >> 6);
  int c0 = cc * 16;
  int n0 = blockIdx.x * 64 + slot;
  bool valid = n0 < NODES;
  int n = valid ? n0 : NODES - 1;
  const float4* cr = (const float4*)(hC + (size_t)n * HD);
  float acc[16];
#pragma unroll
  for (int j = 0; j < 16; j++) acc[j] = b1[c0 + j];
#pragma unroll 4
  for (int q = 0; q < 16; q++) {
    float4 ac = cr[q];
    float cs[4] = {ac.x, ac.y, ac.z, ac.w};
#pragma unroll
    for (int t = 0; t < 4; t++) {
      int k = q * 4 + t;
#pragma unroll
      for (int j = 0; j < 16; j++)
        acc[j] = fmaf(cs[t], W1[k * HD + c0 + j], acc[j]);
    }
  }
#pragma unroll
  for (int j = 0; j < 16; j++) sh[slot * LP + c0 + j] = fmaxf(acc[j], 0.f);
  __syncthreads();
  // stage 2: 8 cols of t2 per cc; stage 3: partial dot with W3
  int d0 = cc * 8;
  float a2[8];
#pragma unroll
  for (int j = 0; j < 8; j++) a2[j] = b2[d0 + j];
#pragma unroll 8
  for (int k = 0; k < 64; k++) {
    float tk = sh[slot * LP + k];
#pragma unroll
    for (int j = 0; j < 8; j++)
      a2[j] = fmaf(tk, W2[k * 32 + d0 + j], a2[j]);
  }
  float part = 0.f;
#pragma unroll
  for (int j = 0; j < 8; j++) part = fmaf(fmaxf(a2[j], 0.f), W3[d0 + j], part);
  sred[cc][slot] = part;
  __syncthreads();
  if (cc == 0 && valid)
    out[n] = sred[0][slot] + sred[1][slot] + sred[2][slot] + sred[3][slot] + b3[0];
}

// ---------------- wave-per-node aggregations ----------------
// 16 edges/iter -> 4 independent row-gathers in flight; epilogue operands hoisted.

#define AGG_BODY(TABLE, WEXPR0, WEXPR1, WEXPR2, WEXPR3)                          \
  float4 acc0 = make_float4(0.f, 0.f, 0.f, 0.f);                                 \
  float4 acc1 = make_float4(0.f, 0.f, 0.f, 0.f);                                 \
  float4 acc2 = make_float4(0.f, 0.f, 0.f, 0.f);                                 \
  float4 acc3 = make_float4(0.f, 0.f, 0.f, 0.f);                                 \
  int last = end - 1;                                                            \
  for (int m = start; m < end; m += 16) {                                        \
    int e0 = m + sub, e1 = e0 + 4, e2 = e0 + 8, e3 = e0 + 12;                    \
    float2 s0 = sa[min(e0, last)], s1 = sa[min(e1, last)];                       \
    float2 s2 = sa[min(e2, last)], s3 = sa[min(e3, last)];                       \
    float w0 = (e0 < end) ? (WEXPR0) : 0.f;                                      \
    float w1 = (e1 < end) ? (WEXPR1) : 0.f;                                      \
    float w2 = (e2 < end) ? (WEXPR2) : 0.f;                                      \
    float w3 = (e3 < end) ? (WEXPR3) : 0.f;                                      \
    float4 v0 = *((const float4*)(TABLE + (size_t)__float_as_int(s0.x) * HD) + col); \
    float4 v1 = *((const float4*)(TABLE + (size_t)__float_as_int(s1.x) * HD) + col); \
    float4 v2 = *((const float4*)(TABLE + (size_t)__float_as_int(s2.x) * HD) + col); \
    float4 v3 = *((const float4*)(TABLE + (size_t)__float_as_int(s3.x) * HD) + col); \
    acc0.x = fmaf(w0, v0.x, acc0.x); acc0.y = fmaf(w0, v0.y, acc0.y);            \
    acc0.z = fmaf(w0, v0.z, acc0.z); acc0.w = fmaf(w0, v0.w, acc0.w);            \
    acc1.x = fmaf(w1, v1.x, acc1.x); acc1.y = fmaf(w1, v1.y, acc1.y);            \
    acc1.z = fmaf(w1, v1.z, acc1.z); acc1.w = fmaf(w1, v1.w, acc1.w);            \
    acc2.x = fmaf(w2, v2.x, acc2.x); acc2.y = fmaf(w2, v2.y, acc2.y);            \
    acc2.z = fmaf(w2, v2.z, acc2.z); acc2.w = fmaf(w2, v2.w, acc2.w);            \
    acc3.x = fmaf(w3, v3.x, acc3.x); acc3.y = fmaf(w3, v3.y, acc3.y);            \
    acc3.z = fmaf(w3, v3.z, acc3.z); acc3.w = fmaf(w3, v3.w, acc3.w);            \
  }                                                                              \
  acc0.x = (acc0.x + acc1.x) + (acc2.x + acc3.x);                                \
  acc0.y = (acc0.y + acc1.y) + (acc2.y + acc3.y);                                \
  acc0.z = (acc0.z + acc1.z) + (acc2.z + acc3.z);                                \
  acc0.w = (acc0.w + acc1.w) + (acc2.w + acc3.w);                                \
  _Pragma("unroll")                                                              \
  for (int off = 16; off <= 32; off <<= 1) {                                     \
    acc0.x += __shfl_xor(acc0.x, off); acc0.y += __shfl_xor(acc0.y, off);        \
    acc0.z += __shfl_xor(acc0.z, off); acc0.w += __shfl_xor(acc0.w, off);        \
  }

__global__ __launch_bounds__(256) void k_agg_att(
    const float2* __restrict__ sa, const int* __restrict__ rowptr,
    const float* __restrict__ hA, const float* __restrict__ hB,
    const float* __restrict__ g, const float* __restrict__ bt,
    float* __restrict__ hC) {
  int lane = threadIdx.x & 63;
  int node = __builtin_amdgcn_readfirstlane(blockIdx.x * 4 + (threadIdx.x >> 6));
  if (node >= NODES) return;
  int start = rowptr[node], end = rowptr[node + 1];
  int sub = lane >> 4, col = lane & 15;
  // hoisted epilogue operands (loaded on all lanes, overlap the gathers)
  float4 gg = ((const float4*)g)[col];
  float4 bb = ((const float4*)bt)[col];
  float4 ha = *((const float4*)(hA + (size_t)node * HD) + col);
  AGG_BODY(hB, s0.y, s1.y, s2.y, s3.y)
  if (lane < 16) {
    float4 v;
    v.x = fmaxf(acc0.x * (gg.x * BN_INV) + bb.x, 0.f) + ha.x;
    v.y = fmaxf(acc0.y * (gg.y * BN_INV) + bb.y, 0.f) + ha.y;
    v.z = fmaxf(acc0.z * (gg.z * BN_INV) + bb.z, 0.f) + ha.z;
    v.w = fmaxf(acc0.w * (gg.w * BN_INV) + bb.w, 0.f) + ha.w;
    *((float4*)(hC + (size_t)node * HD) + col) = v;
  }
}

__global__ __launch_bounds__(256) void k_agg_mean(
    const float2* __restrict__ sa, const int* __restrict__ rowptr,
    const float* __restrict__ hC, float* __restrict__ hM) {
  int lane = threadIdx.x & 63;
  int node = __builtin_amdgcn_readfirstlane(blockIdx.x * 4 + (threadIdx.x >> 6));
  if (node >= NODES) return;
  int start = rowptr[node], end = rowptr[node + 1];
  int sub = lane >> 4, col = lane & 15;
  float rdeg = 1.f / fmaxf((float)(end - start), 1.f);
  AGG_BODY(hC, 1.f, 1.f, 1.f, 1.f)
  if (lane < 16) {
    float4 v;
    v.x = acc0.x * rdeg; v.y = acc0.y * rdeg; v.z = acc0.z * rdeg; v.w = acc0.w * rdeg;
    *((float4*)(hM + (size_t)node * HD) + col) = v;
  }
}

__global__ __launch_bounds__(256) void k_agg_gcn(
    const float2* __restrict__ sa, const int* __restrict__ rowptr,
    const float* __restrict__ dis,
    const float* __restrict__ hA, const float* __restrict__ hBp,
    const float* __restrict__ bg,
    const float* __restrict__ g, const float* __restrict__ bt,
    float* __restrict__ hC) {
  int lane = threadIdx.x & 63;
  int node = __builtin_amdgcn_readfirstlane(blockIdx.x * 4 + (threadIdx.x >> 6));
  if (node >= NODES) return;
  int start = rowptr[node], end = rowptr[node + 1];
  int sub = lane >> 4, col = lane & 15;
  // hoisted epilogue operands
  float di = dis[node];
  float4 sv = *((const float4*)(hBp + (size_t)node * HD) + col);  // self-loop
  float4 gg = ((const float4*)g)[col];
  float4 bb = ((const float4*)bt)[col];
  float4 ha = *((const float4*)(hA + (size_t)node * HD) + col);
  float4 bgv = ((const float4*)bg)[col];
  AGG_BODY(hBp, 1.f, 1.f, 1.f, 1.f)
  if (lane < 16) {
    float4 v;
    v.x = fmaxf((di * (acc0.x + sv.x) + bgv.x) * (gg.x * BN_INV) + bb.x, 0.f) + ha.x;
    v.y = fmaxf((di * (acc0.y + sv.y) + bgv.y) * (gg.y * BN_INV) + bb.y, 0.f) + ha.y;
    v.z = fmaxf((di * (acc0.z + sv.z) + bgv.z) * (gg.z * BN_INV) + bb.z, 0.f) + ha.z;
    v.w = fmaxf((di * (acc0.w + sv.w) + bgv.w) * (gg.w * BN_INV) + bb.w, 0.f) + ha.w;
    *((float4*)(hC + (size_t)node * HD) + col) = v;
  }
}

// ---------------- host launch ----------------

extern "C" void kernel_launch(void* const* d_in, const int* in_sizes, int n_in,
                              void* d_out, int out_size, void* d_ws, size_t ws_size,
                              hipStream_t stream) {
  const float* x      = (const float*)d_in[0];
  const float* ea     = (const float*)d_in[1];
  const int*   ei     = (const int*)d_in[2];
  const float* W_node = (const float*)d_in[3];
  const float* b_node = (const float*)d_in[4];
  // d_in[5], d_in[6]: W_edge/b_edge — unused by the reference output
  const float* W_lin0 = (const float*)d_in[7];
  const float* b_lin0 = (const float*)d_in[8];
  const float* W_att0 = (const float*)d_in[9];
  const float* b_att0 = (const float*)d_in[10];
  const float* W_sl   = (const float*)d_in[11];
  const float* b_sl   = (const float*)d_in[12];
  const float* W_sr   = (const float*)d_in[13];
  const float* W_gcn  = (const float*)d_in[14];
  const float* b_gcn  = (const float*)d_in[15];
  const float* bn_g   = (const float*)d_in[16];  // [3,64]
  const float* bn_b   = (const float*)d_in[17];
  const float* W_r1   = (const float*)d_in[18];
  const float* b_r1   = (const float*)d_in[19];
  const float* W_r2   = (const float*)d_in[20];
  const float* b_r2   = (const float*)d_in[21];
  const float* W_r3   = (const float*)d_in[22];
  const float* b_r3   = (const float*)d_in[23];
  float* out = (float*)d_out;

  char* ws = (char*)d_ws;
  size_t o = 0;
  auto alloc = [&](size_t bytes) -> void* {
    void* p = ws + o;
    o += (bytes + 255) & ~(size_t)255;
    return p;
  };
  int*    deg    = (int*)alloc(NODES * 4);
  int*    rowptr = (int*)alloc((NODES + 1) * 4);
  int*    cur    = (int*)alloc(NODES * 4);
  int*    part   = (int*)alloc(256 * 4);
  float2* sa     = (float2*)alloc((size_t)EDGES * 8);
  float*  hA     = (float*)alloc((size_t)NODES * HD * 4);
  float*  hB     = (float*)alloc((size_t)NODES * HD * 4);
  float*  hC     = (float*)alloc((size_t)NODES * HD * 4);
  float*  hD     = (float*)alloc((size_t)NODES * HD * 4);
  float*  cvec   = (float*)alloc(NODES * 4);
  float*  dvec   = (float*)alloc(NODES * 4);
  float*  dis    = (float*)alloc(NODES * 4);
  (void)ws_size; (void)in_sizes; (void)n_in; (void)out_size;

  const int EB  = (EDGES + 255) / 256;
  const int NT  = (NODES + 63) / 64;     // 64 nodes/block, 256 threads
  const int NBW = (NODES + 3) / 4;       // wave-per-node (4 waves/block)

  hipMemsetAsync(deg, 0, NODES * 4, stream);
  k_hist<<<EB, 256, 0, stream>>>(ei, deg);
  k_scan1<<<NCHUNK, 256, 0, stream>>>(deg, part);
  k_scan2<<<1, 64, 0, stream>>>(part);
  k_scan3<<<NCHUNK, 256, 0, stream>>>(deg, part, rowptr, cur, dis);

  k_lin0<<<NT, 256, 0, stream>>>(x, W_node, b_node, W_lin0, b_lin0, W_att0,
                                 hA, hB, cvec, dvec);
  k_fillatt<<<EB, 256, 0, stream>>>(ei, ea, cvec, dvec, W_att0, b_att0, cur, sa);
  k_agg_att<<<NBW, 256, 0, stream>>>(sa, rowptr, hA, hB,
                                     bn_g + 0 * HD, bn_b + 0 * HD, hC);
  // hB (h0) dead -> reuse as mean buffer
  k_agg_mean<<<NBW, 256, 0, stream>>>(sa, rowptr, hC, hB);
  // t -> hA (h dead), hBp -> hD
  k_sagegcn<<<NT, 256, 0, stream>>>(hB, hC, W_sl, b_sl, W_sr, W_gcn,
                                    bn_g + 1 * HD, bn_b + 1 * HD, dis, hA, hD);
  k_agg_gcn<<<NBW, 256, 0, stream>>>(sa, rowptr, dis, hA, hD, b_gcn,
                                     bn_g + 2 * HD, bn_b + 2 * HD, hC);
  k_reg<<<NT, 256, 0, stream>>>(hC, W_r1, b_r1, W_r2, b_r2, W_r3, b_r3, out);
}